// Round 11
// baseline (2113.648 us; speedup 1.0000x reference)
//
#include <hip/hip_runtime.h>
#include <cmath>

typedef __attribute__((ext_vector_type(4))) float f32x4;
typedef __attribute__((ext_vector_type(8))) short bf16x8;

// matrices are full 256x256 fp32 squares; strict upper of each L is zeroed
#define MSZ 65536

__device__ __forceinline__ unsigned short f2bf(float f){
  unsigned u = __float_as_uint(f);
  unsigned r = (u + 0x7FFFu + ((u >> 16) & 1u)) >> 16;
  return (unsigned short)r;
}

__device__ __forceinline__ float dot4(f32x4 a, f32x4 b){
  return a.x*b.x + a.y*b.y + a.z*b.z + a.w*b.w;
}

__device__ __forceinline__ void tri_decode(int i, int& R, int& C){
  int Rv = (int)((sqrtf(8.f*(float)i + 1.f) - 1.f) * 0.5f);
  while ((Rv+1)*(Rv+2)/2 <= i) ++Rv;
  while (Rv*(Rv+1)/2 > i) --Rv;
  R = Rv; C = i - Rv*(Rv+1)/2;
}

__global__ void k_sentinel(float* __restrict__ out){ out[0] = 123456.0f; }

// ---------------- K0: partition batch indices by label ----------------
__global__ void k0_partition(const int* __restrict__ lab, int* __restrict__ cnt, int* __restrict__ idx){
  __shared__ int lcnt0[8], lcnt1[8];
  int t = threadIdx.x;              // 512 threads, 8 waves
  int w = t >> 6, lane = t & 63;
  int l = lab[t];
  unsigned long long m0 = __ballot(l == 0);
  unsigned long long bm = (lane == 0) ? 0ull : ((1ull << lane) - 1ull);
  int r0 = __popcll(m0 & bm);
  int r1 = __popcll((~m0) & bm);
  if (lane == 0){ lcnt0[w] = __popcll(m0); lcnt1[w] = 64 - __popcll(m0); }
  __syncthreads();
  int base0 = 0, base1 = 0, n0 = 0;
  #pragma unroll
  for (int i = 0; i < 8; ++i){
    if (i < w){ base0 += lcnt0[i]; base1 += lcnt1[i]; }
    n0 += lcnt0[i];
  }
  int pos = (l == 0) ? (base0 + r0) : (n0 + base1 + r1);
  idx[pos] = t;
  if (t == 0){ cnt[0] = n0; cnt[1] = 512 - n0; }
}

// ---------------- K1: per-label means ----------------
__global__ __launch_bounds__(1024) void k1_means(const float* __restrict__ x, const int* __restrict__ lab,
                                                 const int* __restrict__ cnt, float* __restrict__ means){
  __shared__ int labs[512];
  __shared__ float part[8][256];
  int t = threadIdx.x, c = blockIdx.x;
  if (t < 512) labs[t] = lab[t];
  __syncthreads();
  int k = t & 255, bq = t >> 8;
  float s0 = 0.f, s1 = 0.f;
  const float* xc = x + (size_t)c * 256 + k;
  for (int b = bq; b < 512; b += 4){
    float v = xc[(size_t)b * 65536];
    if (labs[b] == 0) s0 += v; else s1 += v;
  }
  part[bq*2+0][k] = s0;
  part[bq*2+1][k] = s1;
  __syncthreads();
  if (t < 256){
    float m0 = part[0][t] + part[2][t] + part[4][t] + part[6][t];
    float m1 = part[1][t] + part[3][t] + part[5][t] + part[7][t];
    float n0 = (float)cnt[0], n1 = (float)cnt[1];
    means[(size_t)c * 256 + t]         = m0 / fmaxf(n0, 1.f);
    means[(size_t)(256 + c) * 256 + t] = m1 / fmaxf(n1, 1.f);
  }
}

// ---------------- K2: per-(channel,label) Gram via MFMA -> Sigma full square, upper zeroed ----------------
__global__ __launch_bounds__(512) void k2_gram(const float* __restrict__ x, const float* __restrict__ cov,
    const float* __restrict__ means, const int* __restrict__ cnt, const int* __restrict__ idx,
    float* __restrict__ sig, int c0){
  __shared__ uint4 XT4[1280];      // 256 k-rows x (4 uint4 data + 1 pad uint4)
  __shared__ float mlds[256];
  int t = threadIdx.x;
  int bid = blockIdx.x;
  int l = bid & 1, c = c0 + (bid >> 1);
  int n0 = cnt[0], n1 = cnt[1];
  int n = l ? n1 : n0;
  int start = l ? n0 : 0;
  if (t < 256) mlds[t] = means[(size_t)(l * 256 + c) * 256 + t];

  f32x4 acc[8][4];
  #pragma unroll
  for (int i = 0; i < 8; ++i)
    #pragma unroll
    for (int jn = 0; jn < 4; ++jn){ f32x4 z; z.x = 0.f; z.y = 0.f; z.z = 0.f; z.w = 0.f; acc[i][jn] = z; }

  int lane = t & 63, wav = t >> 6;
  int wr = wav >> 2, wc = wav & 3;
  int lrow = lane & 15, lhalf = lane >> 4;   // lhalf in [0,4)
  int kq = t & 255, bh = t >> 8;
  int nst = (n + 31) >> 5;

  for (int s = 0; s < nst; ++s){
    __syncthreads();
    unsigned pk[8];
    #pragma unroll
    for (int m = 0; m < 8; ++m){
      int b0 = s * 32 + bh * 16 + 2 * m;
      float v0 = 0.f, v1 = 0.f;
      if (b0 < n)     v0 = x[((size_t)idx[start + b0] * 256 + c) * 256 + kq];
      if (b0 + 1 < n) v1 = x[((size_t)idx[start + b0 + 1] * 256 + c) * 256 + kq];
      pk[m] = (unsigned)f2bf(v0) | ((unsigned)f2bf(v1) << 16);
    }
    XT4[kq * 5 + bh * 2 + 0] = make_uint4(pk[0], pk[1], pk[2], pk[3]);
    XT4[kq * 5 + bh * 2 + 1] = make_uint4(pk[4], pk[5], pk[6], pk[7]);
    __syncthreads();
    bf16x8 af[8], bfr[4];
    #pragma unroll
    for (int i = 0; i < 8; ++i){
      int T = wr * 8 + i;
      af[i] = *reinterpret_cast<const bf16x8*>(&XT4[(T * 16 + lrow) * 5 + lhalf]);
    }
    #pragma unroll
    for (int jn = 0; jn < 4; ++jn){
      int T = wc * 4 + jn;
      bfr[jn] = *reinterpret_cast<const bf16x8*>(&XT4[(T * 16 + lrow) * 5 + lhalf]);
    }
    #pragma unroll
    for (int i = 0; i < 8; ++i)
      #pragma unroll
      for (int jn = 0; jn < 4; ++jn)
        acc[i][jn] = __builtin_amdgcn_mfma_f32_16x16x32_bf16(af[i], bfr[jn], acc[i][jn], 0, 0, 0);
  }
  __syncthreads();

  float invn = 1.0f / fmaxf((float)n, 1.0f);
  float* sigm = sig + (size_t)bid * MSZ;
  #pragma unroll
  for (int i = 0; i < 8; ++i){
    int Rb = (wr * 8 + i) * 16 + lhalf * 4;
    #pragma unroll
    for (int jn = 0; jn < 4; ++jn){
      int Cc = (wc * 4 + jn) * 16 + lrow;
      #pragma unroll
      for (int r = 0; r < 4; ++r){
        int R = Rb + r;
        float v = acc[i][jn][r] * invn + cov[R * 256 + Cc] - mlds[R] * mlds[Cc];
        sigm[R * 256 + Cc] = (Cc <= R) ? v : 0.0f;   // zero strict upper
      }
    }
  }
}

// ---------------- K3a helper: in-LDS 128x128 right-looking Cholesky (r9-verified patterns) ----------------
// LB: 128 x (stride 132). Ld (single, reused per kb): Ld[j*36 + i] = Linv[i][j].
__device__ void factor128_lds(float* __restrict__ LB, float* __restrict__ Ld,
                              int t, float& ldacc){
  for (int kb = 0; kb < 4; ++kb){
    int j0 = kb * 32;
    // ---- (a) wave0: lockstep chol of 32x32 diag + (b) per-lane Linv into Ld
    if (t < 32){
      for (int jj = 0; jj < 32; ++jj){
        float dv = sqrtf(LB[(j0+jj)*132 + j0+jj]);
        float inv = 1.0f / dv;
        if (t == jj){ LB[(j0+jj)*132 + j0+jj] = dv; ldacc += logf(dv); }
        if (t > jj){
          float lv = LB[(j0+t)*132 + j0+jj] * inv;
          LB[(j0+t)*132 + j0+jj] = lv;
          for (int cq = jj+1; cq <= t; ++cq)
            LB[(j0+t)*132 + j0+cq] -= lv * LB[(j0+cq)*132 + j0+jj];
        }
      }
      int j = t;
      for (int i = 0; i < j; ++i) Ld[j*36 + i] = 0.f;
      float xjj = 1.0f / LB[(j0+j)*132 + j0+j];
      Ld[j*36 + j] = xjj;
      for (int i = j+1; i < 32; ++i){
        float s = 0.f;
        for (int p = j; p < i; ++p)
          s += LB[(j0+i)*132 + j0+p] * Ld[j*36 + p];
        Ld[j*36 + i] = -s / LB[(j0+i)*132 + j0+i];
      }
    }
    __syncthreads();
    int nr = 96 - j0;              // panel rows below diag
    if (nr > 0){
      // ---- (c) panel: W = A * Linv^T (parallel GEMM, register-staged, in place)
      bool act = (t < nr * 4);
      int row = j0 + 32 + (t >> 2);
      int g = t & 3;
      if (row > 127) row = 127;
      f32x4 a[8]; float w[8];
      if (act){
        #pragma unroll
        for (int q = 0; q < 8; ++q) a[q] = *(const f32x4*)&LB[row*132 + j0 + 4*q];
        #pragma unroll
        for (int jl = 0; jl < 8; ++jl){
          int j = 8*g + jl;
          float s = 0.f;
          #pragma unroll
          for (int q = 0; q < 8; ++q){
            s += a[q].x * Ld[(4*q+0)*36 + j];
            s += a[q].y * Ld[(4*q+1)*36 + j];
            s += a[q].z * Ld[(4*q+2)*36 + j];
            s += a[q].w * Ld[(4*q+3)*36 + j];
          }
          w[jl] = s;
        }
      }
      __syncthreads();
      if (act){
        #pragma unroll
        for (int jl = 0; jl < 8; ++jl)
          LB[row*132 + j0 + 8*g + jl] = w[jl];
      }
      __syncthreads();
      // ---- (d) trailing rank-32 update: 4x4 tiles over lower tile-triangle
      int nt = nr >> 2;
      int Tt = nt*(nt+1)/2;        // 300 / 136 / 36
      if (t < Tt){
        int R, C; tri_decode(t, R, C);
        int rb = j0+32+4*R, cb = j0+32+4*C;
        float s[16];
        #pragma unroll
        for (int q = 0; q < 16; ++q) s[q] = 0.f;
        #pragma unroll 4
        for (int qc = 0; qc < 8; ++qc){
          f32x4 a0 = *(const f32x4*)&LB[(rb+0)*132 + j0 + 4*qc];
          f32x4 a1 = *(const f32x4*)&LB[(rb+1)*132 + j0 + 4*qc];
          f32x4 a2 = *(const f32x4*)&LB[(rb+2)*132 + j0 + 4*qc];
          f32x4 a3 = *(const f32x4*)&LB[(rb+3)*132 + j0 + 4*qc];
          f32x4 b0 = *(const f32x4*)&LB[(cb+0)*132 + j0 + 4*qc];
          f32x4 b1 = *(const f32x4*)&LB[(cb+1)*132 + j0 + 4*qc];
          f32x4 b2 = *(const f32x4*)&LB[(cb+2)*132 + j0 + 4*qc];
          f32x4 b3 = *(const f32x4*)&LB[(cb+3)*132 + j0 + 4*qc];
          s[0]+=dot4(a0,b0);  s[1]+=dot4(a0,b1);  s[2]+=dot4(a0,b2);  s[3]+=dot4(a0,b3);
          s[4]+=dot4(a1,b0);  s[5]+=dot4(a1,b1);  s[6]+=dot4(a1,b2);  s[7]+=dot4(a1,b3);
          s[8]+=dot4(a2,b0);  s[9]+=dot4(a2,b1);  s[10]+=dot4(a2,b2); s[11]+=dot4(a2,b3);
          s[12]+=dot4(a3,b0); s[13]+=dot4(a3,b1); s[14]+=dot4(a3,b2); s[15]+=dot4(a3,b3);
        }
        #pragma unroll
        for (int i2 = 0; i2 < 4; ++i2)
          #pragma unroll
          for (int jl = 0; jl < 4; ++jl)
            LB[(rb+i2)*132 + cb+jl] -= s[i2*4+jl];
      }
    }
    __syncthreads();
  }
}

// ---------------- K3a: two-level Schur Cholesky, 76.4 KB dynamic LDS (2 blocks/CU) ----------------
// P1 chol(A11) in LDS; P2 TRSM L21=A21*L11^-T (L11 blocks staged from global into LT,
// diag inverses recomputed into Ld); P3 SYRK streamed; P4 chol(A22').
__global__ __launch_bounds__(512) void k3a_chol(float* __restrict__ sig, float* __restrict__ logdet, int c0){
  extern __shared__ float smem[];
  float* LB = smem;                 // 128*132 = 16896 floats
  float* Ld = smem + 16896;         // 1152 floats: Ld[j*36+i] = Linv[i][j] (reused per kb)
  float* LT = smem + 18048;         // 1056 floats: staged 32x32 L blocks (stride 33)
  int t = threadIdx.x;
  int bid = blockIdx.x;
  int l = bid & 1, c = c0 + (bid >> 1);
  float* A = sig + (size_t)bid * MSZ;
  float ldacc = 0.f;

  // ==== P1: load A11, factor in LDS, write L11 ====
  for (int i = t; i < 4096; i += 512){
    int r = i >> 5, q = i & 31;
    *(f32x4*)&LB[r*132 + 4*q] = *(const f32x4*)&A[(size_t)r*256 + 4*q];
  }
  __syncthreads();
  factor128_lds(LB, Ld, t, ldacc);
  for (int i = t; i < 4096; i += 512){
    int r = i >> 5, q = i & 31;
    f32x4 v = *(const f32x4*)&LB[r*132 + 4*q];
    int cb = 4*q;
    v.x = (cb+0 <= r) ? v.x : 0.f;
    v.y = (cb+1 <= r) ? v.y : 0.f;
    v.z = (cb+2 <= r) ? v.z : 0.f;
    v.w = (cb+3 <= r) ? v.w : 0.f;
    *(f32x4*)&A[(size_t)r*256 + 4*q] = v;
  }
  __syncthreads();

  // ==== P2: TRSM L21 = A21 * L11^-T; W in LB; L11 staged from global ====
  {
    int r2 = t >> 2, g = t & 3;
    for (int kb = 0; kb < 4; ++kb){
      f32x4 v0 = *(const f32x4*)&A[(size_t)(128+r2)*256 + 32*kb + 8*g];
      f32x4 v1 = *(const f32x4*)&A[(size_t)(128+r2)*256 + 32*kb + 8*g + 4];
      float accv[8] = {v0.x, v0.y, v0.z, v0.w, v1.x, v1.y, v1.z, v1.w};
      for (int p = 0; p < kb; ++p){
        __syncthreads();   // prior LT/Ld consumers done
        for (int i = t; i < 1024; i += 512){
          int j = i & 31, q = i >> 5;
          LT[q*33 + j] = A[(size_t)(32*kb + j)*256 + 32*p + q];   // LT[q][j] = L11[32kb+j][32p+q]
        }
        __syncthreads();
        f32x4 wv[8];
        #pragma unroll
        for (int q = 0; q < 8; ++q) wv[q] = *(const f32x4*)&LB[r2*132 + 32*p + 4*q];
        #pragma unroll
        for (int q4 = 0; q4 < 8; ++q4)
          #pragma unroll
          for (int jl = 0; jl < 8; ++jl)
            accv[jl] -= wv[q4].x * LT[(4*q4+0)*33 + 8*g+jl]
                      + wv[q4].y * LT[(4*q4+1)*33 + 8*g+jl]
                      + wv[q4].z * LT[(4*q4+2)*33 + 8*g+jl]
                      + wv[q4].w * LT[(4*q4+3)*33 + 8*g+jl];
      }
      // deposit partially-reduced block into LB
      #pragma unroll
      for (int jl = 0; jl < 8; ++jl) LB[r2*132 + 32*kb + 8*g + jl] = accv[jl];
      __syncthreads();   // accv visible; prior LT consumers done
      // stage diag L block of column kb
      for (int i = t; i < 1024; i += 512){
        int cc = i >> 5, p = i & 31;
        LT[cc*33 + p] = A[(size_t)(32*kb + cc)*256 + 32*kb + p];  // L[cc][p]
      }
      __syncthreads();
      // read full 32-wide row segment; wave0 also recomputes Linv from LT into Ld
      f32x4 vv[8];
      #pragma unroll
      for (int q = 0; q < 8; ++q) vv[q] = *(const f32x4*)&LB[r2*132 + 32*kb + 4*q];
      if (t < 32){
        int j = t;
        for (int i = 0; i < j; ++i) Ld[j*36 + i] = 0.f;
        float xjj = 1.0f / LT[j*33 + j];
        Ld[j*36 + j] = xjj;
        for (int i = j+1; i < 32; ++i){
          float s = 0.f;
          for (int p = j; p < i; ++p)
            s += LT[i*33 + p] * Ld[j*36 + p];
          Ld[j*36 + i] = -s / LT[i*33 + i];
        }
      }
      __syncthreads();   // Ld ready; vv reads complete
      #pragma unroll
      for (int jl = 0; jl < 8; ++jl){
        int j = 8*g + jl;
        float s = 0.f;
        #pragma unroll
        for (int q = 0; q < 8; ++q){
          s += vv[q].x * Ld[(4*q+0)*36 + j];
          s += vv[q].y * Ld[(4*q+1)*36 + j];
          s += vv[q].z * Ld[(4*q+2)*36 + j];
          s += vv[q].w * Ld[(4*q+3)*36 + j];
        }
        LB[r2*132 + 32*kb + 8*g + jl] = s;
      }
      __syncthreads();
    }
    // write L21 (dense)
    for (int i = t; i < 4096; i += 512){
      int rr = i >> 5, q = i & 31;
      *(f32x4*)&A[(size_t)(128+rr)*256 + 4*q] = *(const f32x4*)&LB[rr*132 + 4*q];
    }
  }

  // ==== P3: SYRK A22' = A22 - L21*L21^T (stream A22, dots vs LDS L21, regs hold) ====
  float s1[16], s2[16];
  int R1 = 0, C1 = 0, R2 = 0, C2 = 0;
  bool v1 = (t < 528), v2 = (t < 16);
  if (v1) tri_decode(t, R1, C1);
  if (v2) tri_decode(512 + t, R2, C2);
  #pragma unroll
  for (int q = 0; q < 16; ++q){ s1[q] = 0.f; s2[q] = 0.f; }
  if (v1){
    for (int qc = 0; qc < 32; ++qc){
      f32x4 a0 = *(const f32x4*)&LB[(4*R1+0)*132 + 4*qc];
      f32x4 a1 = *(const f32x4*)&LB[(4*R1+1)*132 + 4*qc];
      f32x4 a2 = *(const f32x4*)&LB[(4*R1+2)*132 + 4*qc];
      f32x4 a3 = *(const f32x4*)&LB[(4*R1+3)*132 + 4*qc];
      f32x4 b0 = *(const f32x4*)&LB[(4*C1+0)*132 + 4*qc];
      f32x4 b1 = *(const f32x4*)&LB[(4*C1+1)*132 + 4*qc];
      f32x4 b2 = *(const f32x4*)&LB[(4*C1+2)*132 + 4*qc];
      f32x4 b3 = *(const f32x4*)&LB[(4*C1+3)*132 + 4*qc];
      s1[0]+=dot4(a0,b0);  s1[1]+=dot4(a0,b1);  s1[2]+=dot4(a0,b2);  s1[3]+=dot4(a0,b3);
      s1[4]+=dot4(a1,b0);  s1[5]+=dot4(a1,b1);  s1[6]+=dot4(a1,b2);  s1[7]+=dot4(a1,b3);
      s1[8]+=dot4(a2,b0);  s1[9]+=dot4(a2,b1);  s1[10]+=dot4(a2,b2); s1[11]+=dot4(a2,b3);
      s1[12]+=dot4(a3,b0); s1[13]+=dot4(a3,b1); s1[14]+=dot4(a3,b2); s1[15]+=dot4(a3,b3);
    }
    #pragma unroll
    for (int i2 = 0; i2 < 4; ++i2){
      f32x4 av = *(const f32x4*)&A[(size_t)(128+4*R1+i2)*256 + 128 + 4*C1];
      s1[i2*4+0] = av.x - s1[i2*4+0];
      s1[i2*4+1] = av.y - s1[i2*4+1];
      s1[i2*4+2] = av.z - s1[i2*4+2];
      s1[i2*4+3] = av.w - s1[i2*4+3];
    }
  }
  if (v2){
    for (int qc = 0; qc < 32; ++qc){
      f32x4 a0 = *(const f32x4*)&LB[(4*R2+0)*132 + 4*qc];
      f32x4 a1 = *(const f32x4*)&LB[(4*R2+1)*132 + 4*qc];
      f32x4 a2 = *(const f32x4*)&LB[(4*R2+2)*132 + 4*qc];
      f32x4 a3 = *(const f32x4*)&LB[(4*R2+3)*132 + 4*qc];
      f32x4 b0 = *(const f32x4*)&LB[(4*C2+0)*132 + 4*qc];
      f32x4 b1 = *(const f32x4*)&LB[(4*C2+1)*132 + 4*qc];
      f32x4 b2 = *(const f32x4*)&LB[(4*C2+2)*132 + 4*qc];
      f32x4 b3 = *(const f32x4*)&LB[(4*C2+3)*132 + 4*qc];
      s2[0]+=dot4(a0,b0);  s2[1]+=dot4(a0,b1);  s2[2]+=dot4(a0,b2);  s2[3]+=dot4(a0,b3);
      s2[4]+=dot4(a1,b0);  s2[5]+=dot4(a1,b1);  s2[6]+=dot4(a1,b2);  s2[7]+=dot4(a1,b3);
      s2[8]+=dot4(a2,b0);  s2[9]+=dot4(a2,b1);  s2[10]+=dot4(a2,b2); s2[11]+=dot4(a2,b3);
      s2[12]+=dot4(a3,b0); s2[13]+=dot4(a3,b1); s2[14]+=dot4(a3,b2); s2[15]+=dot4(a3,b3);
    }
    #pragma unroll
    for (int i2 = 0; i2 < 4; ++i2){
      f32x4 av = *(const f32x4*)&A[(size_t)(128+4*R2+i2)*256 + 128 + 4*C2];
      s2[i2*4+0] = av.x - s2[i2*4+0];
      s2[i2*4+1] = av.y - s2[i2*4+1];
      s2[i2*4+2] = av.z - s2[i2*4+2];
      s2[i2*4+3] = av.w - s2[i2*4+3];
    }
  }
  __syncthreads();     // all reads of LB (L21) complete
  if (v1){
    #pragma unroll
    for (int i2 = 0; i2 < 4; ++i2)
      #pragma unroll
      for (int jl = 0; jl < 4; ++jl)
        LB[(4*R1+i2)*132 + 4*C1+jl] = s1[i2*4+jl];
  }
  if (v2){
    #pragma unroll
    for (int i2 = 0; i2 < 4; ++i2)
      #pragma unroll
      for (int jl = 0; jl < 4; ++jl)
        LB[(4*R2+i2)*132 + 4*C2+jl] = s2[i2*4+jl];
  }
  __syncthreads();

  // ==== P4: factor A22' in LDS; write L22 ====
  factor128_lds(LB, Ld, t, ldacc);
  for (int i = t; i < 4096; i += 512){
    int r = i >> 5, q = i & 31;
    f32x4 v = *(const f32x4*)&LB[r*132 + 4*q];
    int cb = 4*q;
    v.x = (cb+0 <= r) ? v.x : 0.f;
    v.y = (cb+1 <= r) ? v.y : 0.f;
    v.z = (cb+2 <= r) ? v.z : 0.f;
    v.w = (cb+3 <= r) ? v.w : 0.f;
    *(f32x4*)&A[(size_t)(128+r)*256 + 128 + 4*q] = v;
  }
  // logdet: reduce wave0 lanes' per-column partials
  if (t < 32){
    float v = ldacc;
    #pragma unroll
    for (int m = 1; m < 32; m <<= 1) v += __shfl_xor(v, m);
    if (t == 0) logdet[l * 256 + c] = 2.0f * v;
  }
}

// ---------------- K3b: TRSM L1 W = L0 in place, column-per-thread; trp = ||W||_F^2 ----------------
__global__ __launch_bounds__(256) void k3b_trsm(float* __restrict__ sig, float* __restrict__ trp, int c0){
  __shared__ float L1blk[32 * 256];   // 32 KB
  __shared__ float redw[4];
  int t = threadIdx.x, b = blockIdx.x;
  int lane = t & 63, wav = t >> 6;
  const float* L1 = sig + (size_t)(b * 2 + 1) * MSZ;
  float* W = sig + (size_t)(b * 2) * MSZ;     // starts as L0, becomes W
  float tracc = 0.f;

  for (int RB = 0; RB < 8; ++RB){
    int r0 = RB * 32;
    __syncthreads();
    for (int i = t; i < 32 * 256; i += 256)
      L1blk[i] = L1[(size_t)(r0 + (i >> 8)) * 256 + (i & 255)];
    __syncthreads();

    float acc[32];
    #pragma unroll
    for (int r = 0; r < 32; ++r) acc[r] = W[(size_t)(r0 + r) * 256 + t];

    for (int p = 0; p < r0; p += 8){
      float wv[8];
      #pragma unroll
      for (int q = 0; q < 8; ++q) wv[q] = W[(size_t)(p + q) * 256 + t];
      #pragma unroll
      for (int r = 0; r < 32; ++r){
        const f32x4 La = *(const f32x4*)&L1blk[r * 256 + p];
        const f32x4 Lb = *(const f32x4*)&L1blk[r * 256 + p + 4];
        acc[r] -= La.x * wv[0] + La.y * wv[1] + La.z * wv[2] + La.w * wv[3]
                + Lb.x * wv[4] + Lb.y * wv[5] + Lb.z * wv[6] + Lb.w * wv[7];
      }
    }
    // in-block forward substitution (column-private, no barriers)
    #pragma unroll
    for (int rr = 0; rr < 32; ++rr){
      float v = acc[rr];
      #pragma unroll
      for (int q = 0; q < rr; ++q)
        v -= L1blk[rr * 256 + r0 + q] * acc[q];
      v /= L1blk[rr * 256 + r0 + rr];
      acc[rr] = v;
      tracc += v * v;
      W[(size_t)(r0 + rr) * 256 + t] = v;
    }
  }
  #pragma unroll
  for (int m = 1; m < 64; m <<= 1) tracc += __shfl_xor(tracc, m);
  if (lane == 0) redw[wav] = tracc;
  __syncthreads();
  if (t == 0) trp[c0 + b] = redw[0] + redw[1] + redw[2] + redw[3];
}

// ---------------- K3c: quad = ||L1^-1 d||^2; final per-channel kl ----------------
__global__ __launch_bounds__(64) void k3c_quad(const float* __restrict__ means, const float* __restrict__ sig,
    const float* __restrict__ trp, const float* __restrict__ logdet, float* __restrict__ klp, int c0){
  __shared__ float y[256];
  int t = threadIdx.x, b = blockIdx.x;
  int c = c0 + b;
  const float* L1 = sig + (size_t)(b * 2 + 1) * MSZ;
  const float* m1p = means + (size_t)(256 + c) * 256;
  const float* m0p = means + (size_t)c * 256;

  for (int r = 0; r < 256; ++r){
    float part = 0.f;
    for (int p = t; p < r; p += 64)
      part += L1[(size_t)r * 256 + p] * y[p];
    #pragma unroll
    for (int m = 1; m < 64; m <<= 1) part += __shfl_xor(part, m);
    if (t == 0)
      y[r] = ((m1p[r] - m0p[r]) - part) / L1[(size_t)r * 256 + r];
    __syncthreads();
  }
  float q = 0.f;
  #pragma unroll
  for (int i = 0; i < 4; ++i){ float v = y[t + 64 * i]; q += v * v; }
  #pragma unroll
  for (int m = 1; m < 64; m <<= 1) q += __shfl_xor(q, m);
  if (t == 0)
    klp[c] = 0.5f * (trp[c] + q - 256.0f + logdet[256 + c] - logdet[c]);
}

// ---------------- K4: final reduce + scale ----------------
__global__ void k4_final(const float* __restrict__ klp, const int* __restrict__ cnt, float* __restrict__ out){
  __shared__ float red[256];
  int t = threadIdx.x;
  red[t] = klp[t];
  __syncthreads();
  for (int s = 128; s > 0; s >>= 1){
    if (t < s) red[t] += red[t + s];
    __syncthreads();
  }
  if (t == 0){
    float n0 = (float)cnt[0], n1 = (float)cnt[1];
    out[0] = red[0] * n0 * n1 / 256.0f / 512.0f / 512.0f;
  }
}

extern "C" void kernel_launch(void* const* d_in, const int* in_sizes, int n_in,
                              void* d_out, int out_size, void* d_ws, size_t ws_size,
                              hipStream_t stream){
  (void)in_sizes; (void)n_in; (void)out_size;
  const float* mu  = (const float*)d_in[0];
  const float* cov = (const float*)d_in[1];
  const int*   lab = (const int*)d_in[2];
  float* out = (float*)d_out;
  char* ws = (char*)d_ws;
  // ws layout (bytes):
  // means  @ 0        (524288)   trp @ 524288 (1024)   klp @ 525312 (1024)
  // logdet @ 526336   (2048)     cnt @ 528384 (8)      idx @ 528392 (2048)
  // sig    @ 1048576  (ch*2 full 256x256 fp32 squares)
  float* means  = (float*)ws;
  float* trp    = (float*)(ws + 524288);
  float* klp    = (float*)(ws + 525312);
  float* logdet = (float*)(ws + 526336);
  int*   cnt    = (int*)  (ws + 528384);
  int*   idx    = (int*)  (ws + 528392);
  float* sig    = (float*)(ws + 1048576);
  const size_t base = 1048576;

  int ch = 0;
  if      (ws_size >= base + (size_t)256 * 2 * MSZ * 4) ch = 256;
  else if (ws_size >= base + (size_t)64  * 2 * MSZ * 4) ch = 64;
  else if (ws_size >= base + (size_t)16  * 2 * MSZ * 4) ch = 16;
  else if (ws_size >= base + (size_t)4   * 2 * MSZ * 4) ch = 4;
  else if (ws_size >= base + (size_t)1   * 2 * MSZ * 4) ch = 1;
  if (ch == 0){
    k_sentinel<<<1, 1, 0, stream>>>(out);
    return;
  }

  const int k3a_lds = 19104 * 4;   // 76416 B dynamic LDS -> 2 blocks/CU
  (void)hipFuncSetAttribute((const void*)k3a_chol,
                            hipFuncAttributeMaxDynamicSharedMemorySize, k3a_lds);

  k0_partition<<<1, 512, 0, stream>>>(lab, cnt, idx);
  k1_means<<<256, 1024, 0, stream>>>(mu, lab, cnt, means);
  for (int c0 = 0; c0 < 256; c0 += ch){
    k2_gram<<<ch * 2, 512, 0, stream>>>(mu, cov, means, cnt, idx, sig, c0);
    k3a_chol<<<ch * 2, 512, k3a_lds, stream>>>(sig, logdet, c0);
    k3b_trsm<<<ch, 256, 0, stream>>>(sig, trp, c0);
    k3c_quad<<<ch, 64, 0, stream>>>(means, sig, trp, logdet, klp, c0);
  }
  k4_final<<<1, 256, 0, stream>>>(klp, cnt, out);
}

// Round 12
// 1383.443 us; speedup vs baseline: 1.5278x; 1.5278x over previous
//
#include <hip/hip_runtime.h>
#include <cmath>

typedef __attribute__((ext_vector_type(4))) float f32x4;
typedef __attribute__((ext_vector_type(8))) short bf16x8;

// matrices are full 256x256 fp32 squares; strict upper of each L is zeroed
#define MSZ 65536

__device__ __forceinline__ unsigned short f2bf(float f){
  unsigned u = __float_as_uint(f);
  unsigned r = (u + 0x7FFFu + ((u >> 16) & 1u)) >> 16;
  return (unsigned short)r;
}

__device__ __forceinline__ float dot4(f32x4 a, f32x4 b){
  return a.x*b.x + a.y*b.y + a.z*b.z + a.w*b.w;
}

__device__ __forceinline__ void tri_decode(int i, int& R, int& C){
  int Rv = (int)((sqrtf(8.f*(float)i + 1.f) - 1.f) * 0.5f);
  while ((Rv+1)*(Rv+2)/2 <= i) ++Rv;
  while (Rv*(Rv+1)/2 > i) --Rv;
  R = Rv; C = i - Rv*(Rv+1)/2;
}

__global__ void k_sentinel(float* __restrict__ out){ out[0] = 123456.0f; }

// ---------------- K0: partition batch indices by label ----------------
__global__ void k0_partition(const int* __restrict__ lab, int* __restrict__ cnt, int* __restrict__ idx){
  __shared__ int lcnt0[8], lcnt1[8];
  int t = threadIdx.x;              // 512 threads, 8 waves
  int w = t >> 6, lane = t & 63;
  int l = lab[t];
  unsigned long long m0 = __ballot(l == 0);
  unsigned long long bm = (lane == 0) ? 0ull : ((1ull << lane) - 1ull);
  int r0 = __popcll(m0 & bm);
  int r1 = __popcll((~m0) & bm);
  if (lane == 0){ lcnt0[w] = __popcll(m0); lcnt1[w] = 64 - __popcll(m0); }
  __syncthreads();
  int base0 = 0, base1 = 0, n0 = 0;
  #pragma unroll
  for (int i = 0; i < 8; ++i){
    if (i < w){ base0 += lcnt0[i]; base1 += lcnt1[i]; }
    n0 += lcnt0[i];
  }
  int pos = (l == 0) ? (base0 + r0) : (n0 + base1 + r1);
  idx[pos] = t;
  if (t == 0){ cnt[0] = n0; cnt[1] = 512 - n0; }
}

// ---------------- K1: per-label means ----------------
__global__ __launch_bounds__(1024) void k1_means(const float* __restrict__ x, const int* __restrict__ lab,
                                                 const int* __restrict__ cnt, float* __restrict__ means){
  __shared__ int labs[512];
  __shared__ float part[8][256];
  int t = threadIdx.x, c = blockIdx.x;
  if (t < 512) labs[t] = lab[t];
  __syncthreads();
  int k = t & 255, bq = t >> 8;
  float s0 = 0.f, s1 = 0.f;
  const float* xc = x + (size_t)c * 256 + k;
  for (int b = bq; b < 512; b += 4){
    float v = xc[(size_t)b * 65536];
    if (labs[b] == 0) s0 += v; else s1 += v;
  }
  part[bq*2+0][k] = s0;
  part[bq*2+1][k] = s1;
  __syncthreads();
  if (t < 256){
    float m0 = part[0][t] + part[2][t] + part[4][t] + part[6][t];
    float m1 = part[1][t] + part[3][t] + part[5][t] + part[7][t];
    float n0 = (float)cnt[0], n1 = (float)cnt[1];
    means[(size_t)c * 256 + t]         = m0 / fmaxf(n0, 1.f);
    means[(size_t)(256 + c) * 256 + t] = m1 / fmaxf(n1, 1.f);
  }
}

// ---------------- K2: per-(channel,label) Gram via MFMA -> Sigma full square, upper zeroed ----------------
__global__ __launch_bounds__(512) void k2_gram(const float* __restrict__ x, const float* __restrict__ cov,
    const float* __restrict__ means, const int* __restrict__ cnt, const int* __restrict__ idx,
    float* __restrict__ sig, int c0){
  __shared__ uint4 XT4[1280];      // 256 k-rows x (4 uint4 data + 1 pad uint4)
  __shared__ float mlds[256];
  int t = threadIdx.x;
  int bid = blockIdx.x;
  int l = bid & 1, c = c0 + (bid >> 1);
  int n0 = cnt[0], n1 = cnt[1];
  int n = l ? n1 : n0;
  int start = l ? n0 : 0;
  if (t < 256) mlds[t] = means[(size_t)(l * 256 + c) * 256 + t];

  f32x4 acc[8][4];
  #pragma unroll
  for (int i = 0; i < 8; ++i)
    #pragma unroll
    for (int jn = 0; jn < 4; ++jn){ f32x4 z; z.x = 0.f; z.y = 0.f; z.z = 0.f; z.w = 0.f; acc[i][jn] = z; }

  int lane = t & 63, wav = t >> 6;
  int wr = wav >> 2, wc = wav & 3;
  int lrow = lane & 15, lhalf = lane >> 4;   // lhalf in [0,4)
  int kq = t & 255, bh = t >> 8;
  int nst = (n + 31) >> 5;

  for (int s = 0; s < nst; ++s){
    __syncthreads();
    unsigned pk[8];
    #pragma unroll
    for (int m = 0; m < 8; ++m){
      int b0 = s * 32 + bh * 16 + 2 * m;
      float v0 = 0.f, v1 = 0.f;
      if (b0 < n)     v0 = x[((size_t)idx[start + b0] * 256 + c) * 256 + kq];
      if (b0 + 1 < n) v1 = x[((size_t)idx[start + b0 + 1] * 256 + c) * 256 + kq];
      pk[m] = (unsigned)f2bf(v0) | ((unsigned)f2bf(v1) << 16);
    }
    XT4[kq * 5 + bh * 2 + 0] = make_uint4(pk[0], pk[1], pk[2], pk[3]);
    XT4[kq * 5 + bh * 2 + 1] = make_uint4(pk[4], pk[5], pk[6], pk[7]);
    __syncthreads();
    bf16x8 af[8], bfr[4];
    #pragma unroll
    for (int i = 0; i < 8; ++i){
      int T = wr * 8 + i;
      af[i] = *reinterpret_cast<const bf16x8*>(&XT4[(T * 16 + lrow) * 5 + lhalf]);
    }
    #pragma unroll
    for (int jn = 0; jn < 4; ++jn){
      int T = wc * 4 + jn;
      bfr[jn] = *reinterpret_cast<const bf16x8*>(&XT4[(T * 16 + lrow) * 5 + lhalf]);
    }
    #pragma unroll
    for (int i = 0; i < 8; ++i)
      #pragma unroll
      for (int jn = 0; jn < 4; ++jn)
        acc[i][jn] = __builtin_amdgcn_mfma_f32_16x16x32_bf16(af[i], bfr[jn], acc[i][jn], 0, 0, 0);
  }
  __syncthreads();

  float invn = 1.0f / fmaxf((float)n, 1.0f);
  float* sigm = sig + (size_t)bid * MSZ;
  #pragma unroll
  for (int i = 0; i < 8; ++i){
    int Rb = (wr * 8 + i) * 16 + lhalf * 4;
    #pragma unroll
    for (int jn = 0; jn < 4; ++jn){
      int Cc = (wc * 4 + jn) * 16 + lrow;
      #pragma unroll
      for (int r = 0; r < 4; ++r){
        int R = Rb + r;
        float v = acc[i][jn][r] * invn + cov[R * 256 + Cc] - mlds[R] * mlds[Cc];
        sigm[R * 256 + Cc] = (Cc <= R) ? v : 0.0f;   // zero strict upper
      }
    }
  }
}

// ---------------- K3a helper: in-LDS 128x128 right-looking Cholesky ----------------
// LB: 128 x (stride 132). Diag: LDS-lockstep chol32 (r9/r11-verified, runtime loops).
// Panel: per-row register forward substitution (r9-P2-verified pattern). No Linv anywhere.
__device__ void factor128_v12(float* __restrict__ LB, int t, float& ldacc){
  for (int kb = 0; kb < 4; ++kb){
    int j0 = kb * 32;
    // ---- (a) wave0: lockstep chol of 32x32 diag block (LDS-direct, runtime loops)
    if (t < 32){
      for (int jj = 0; jj < 32; ++jj){
        float dv = sqrtf(LB[(j0+jj)*132 + j0+jj]);
        float inv = 1.0f / dv;
        if (t == jj){ LB[(j0+jj)*132 + j0+jj] = dv; ldacc += logf(dv); }
        if (t > jj){
          float lv = LB[(j0+t)*132 + j0+jj] * inv;
          LB[(j0+t)*132 + j0+jj] = lv;
          for (int cq = jj+1; cq <= t; ++cq)
            LB[(j0+t)*132 + j0+cq] -= lv * LB[(j0+cq)*132 + j0+jj];
        }
      }
    }
    __syncthreads();
    int nr = 96 - j0;              // panel rows below diag
    if (nr > 0){
      // ---- (b) panel: per-row forward substitution (register w, broadcast LDS reads)
      if (t < nr){
        int row = j0 + 32 + t;
        float w[32];
        #pragma unroll
        for (int q = 0; q < 8; ++q){
          f32x4 v = *(const f32x4*)&LB[row*132 + j0 + 4*q];
          w[4*q] = v.x; w[4*q+1] = v.y; w[4*q+2] = v.z; w[4*q+3] = v.w;
        }
        #pragma unroll
        for (int cc = 0; cc < 32; ++cc){
          float s = w[cc];
          #pragma unroll
          for (int p = 0; p < cc; ++p) s -= LB[(j0+cc)*132 + j0 + p] * w[p];
          w[cc] = s / LB[(j0+cc)*132 + j0 + cc];
        }
        #pragma unroll
        for (int q = 0; q < 8; ++q){
          f32x4 v; v.x = w[4*q]; v.y = w[4*q+1]; v.z = w[4*q+2]; v.w = w[4*q+3];
          *(f32x4*)&LB[row*132 + j0 + 4*q] = v;
        }
      }
      __syncthreads();
      // ---- (c) trailing rank-32 update: 4x4 tiles over lower tile-triangle
      int nt = nr >> 2;
      int Tt = nt*(nt+1)/2;        // 300 / 136 / 36
      if (t < Tt){
        int R, C; tri_decode(t, R, C);
        int rb = j0+32+4*R, cb = j0+32+4*C;
        float s[16];
        #pragma unroll
        for (int q = 0; q < 16; ++q) s[q] = 0.f;
        #pragma unroll 4
        for (int qc = 0; qc < 8; ++qc){
          f32x4 a0 = *(const f32x4*)&LB[(rb+0)*132 + j0 + 4*qc];
          f32x4 a1 = *(const f32x4*)&LB[(rb+1)*132 + j0 + 4*qc];
          f32x4 a2 = *(const f32x4*)&LB[(rb+2)*132 + j0 + 4*qc];
          f32x4 a3 = *(const f32x4*)&LB[(rb+3)*132 + j0 + 4*qc];
          f32x4 b0 = *(const f32x4*)&LB[(cb+0)*132 + j0 + 4*qc];
          f32x4 b1 = *(const f32x4*)&LB[(cb+1)*132 + j0 + 4*qc];
          f32x4 b2 = *(const f32x4*)&LB[(cb+2)*132 + j0 + 4*qc];
          f32x4 b3 = *(const f32x4*)&LB[(cb+3)*132 + j0 + 4*qc];
          s[0]+=dot4(a0,b0);  s[1]+=dot4(a0,b1);  s[2]+=dot4(a0,b2);  s[3]+=dot4(a0,b3);
          s[4]+=dot4(a1,b0);  s[5]+=dot4(a1,b1);  s[6]+=dot4(a1,b2);  s[7]+=dot4(a1,b3);
          s[8]+=dot4(a2,b0);  s[9]+=dot4(a2,b1);  s[10]+=dot4(a2,b2); s[11]+=dot4(a2,b3);
          s[12]+=dot4(a3,b0); s[13]+=dot4(a3,b1); s[14]+=dot4(a3,b2); s[15]+=dot4(a3,b3);
        }
        #pragma unroll
        for (int i2 = 0; i2 < 4; ++i2)
          #pragma unroll
          for (int jl = 0; jl < 4; ++jl)
            LB[(rb+i2)*132 + cb+jl] -= s[i2*4+jl];
      }
    }
    __syncthreads();
  }
}

// ---------------- K3a: two-level Schur Cholesky, 71.8 KB dynamic LDS ----------------
// P1 chol(A11) in LDS; P2 TRSM L21 (L11 blocks staged into LT, per-row substitution);
// P3 SYRK streamed from global vs LDS L21; P4 chol(A22').
__global__ __launch_bounds__(512) void k3a_chol(float* __restrict__ sig, float* __restrict__ logdet, int c0){
  extern __shared__ float smem[];
  float* LB = smem;                 // 128*132 = 16896 floats
  float* LT = smem + 16896;         // 1056 floats (staged 32x32 L blocks, stride 33)
  int t = threadIdx.x;
  int bid = blockIdx.x;
  int l = bid & 1, c = c0 + (bid >> 1);
  float* A = sig + (size_t)bid * MSZ;
  float ldacc = 0.f;

  // ==== P1: load A11, factor in LDS, write L11 ====
  for (int i = t; i < 4096; i += 512){
    int r = i >> 5, q = i & 31;
    *(f32x4*)&LB[r*132 + 4*q] = *(const f32x4*)&A[(size_t)r*256 + 4*q];
  }
  __syncthreads();
  factor128_v12(LB, t, ldacc);
  for (int i = t; i < 4096; i += 512){
    int r = i >> 5, q = i & 31;
    f32x4 v = *(const f32x4*)&LB[r*132 + 4*q];
    int cb = 4*q;
    v.x = (cb+0 <= r) ? v.x : 0.f;
    v.y = (cb+1 <= r) ? v.y : 0.f;
    v.z = (cb+2 <= r) ? v.z : 0.f;
    v.w = (cb+3 <= r) ? v.w : 0.f;
    *(f32x4*)&A[(size_t)r*256 + 4*q] = v;
  }
  __syncthreads();

  // ==== P2: TRSM L21 = A21 * L11^-T; W in LB; L11 blocks staged from global ====
  {
    int r2 = t >> 2, g = t & 3;
    for (int kb = 0; kb < 4; ++kb){
      f32x4 v0 = *(const f32x4*)&A[(size_t)(128+r2)*256 + 32*kb + 8*g];
      f32x4 v1 = *(const f32x4*)&A[(size_t)(128+r2)*256 + 32*kb + 8*g + 4];
      float accv[8] = {v0.x, v0.y, v0.z, v0.w, v1.x, v1.y, v1.z, v1.w};
      for (int p = 0; p < kb; ++p){
        __syncthreads();   // prior LT readers done
        for (int i = t; i < 1024; i += 512){
          int j = i & 31, q = i >> 5;
          LT[q*33 + j] = A[(size_t)(32*kb + j)*256 + 32*p + q];   // LT[q][j] = L11[32kb+j][32p+q]
        }
        __syncthreads();
        f32x4 wv[8];
        #pragma unroll
        for (int q = 0; q < 8; ++q) wv[q] = *(const f32x4*)&LB[r2*132 + 32*p + 4*q];
        #pragma unroll
        for (int q4 = 0; q4 < 8; ++q4)
          #pragma unroll
          for (int jl = 0; jl < 8; ++jl)
            accv[jl] -= wv[q4].x * LT[(4*q4+0)*33 + 8*g+jl]
                      + wv[q4].y * LT[(4*q4+1)*33 + 8*g+jl]
                      + wv[q4].z * LT[(4*q4+2)*33 + 8*g+jl]
                      + wv[q4].w * LT[(4*q4+3)*33 + 8*g+jl];
      }
      #pragma unroll
      for (int jl = 0; jl < 8; ++jl) LB[r2*132 + 32*kb + 8*g + jl] = accv[jl];
      __syncthreads();   // LB writes visible; prior LT readers done
      // stage diag L block of column kb
      for (int i = t; i < 1024; i += 512){
        int cc = i >> 5, p = i & 31;
        LT[cc*33 + p] = A[(size_t)(32*kb + cc)*256 + 32*kb + p];  // L[cc][p]
      }
      __syncthreads();
      if (t < 128){      // per-row substitution vs diag block
        float w[32];
        #pragma unroll
        for (int q = 0; q < 8; ++q){
          f32x4 v = *(const f32x4*)&LB[t*132 + 32*kb + 4*q];
          w[4*q] = v.x; w[4*q+1] = v.y; w[4*q+2] = v.z; w[4*q+3] = v.w;
        }
        #pragma unroll
        for (int cc = 0; cc < 32; ++cc){
          float s = w[cc];
          #pragma unroll
          for (int p = 0; p < cc; ++p) s -= LT[cc*33 + p] * w[p];
          w[cc] = s / LT[cc*33 + cc];
        }
        #pragma unroll
        for (int q = 0; q < 8; ++q){
          f32x4 v; v.x = w[4*q]; v.y = w[4*q+1]; v.z = w[4*q+2]; v.w = w[4*q+3];
          *(f32x4*)&LB[t*132 + 32*kb + 4*q] = v;
        }
      }
      __syncthreads();
    }
    // write L21 (dense)
    for (int i = t; i < 4096; i += 512){
      int rr = i >> 5, q = i & 31;
      *(f32x4*)&A[(size_t)(128+rr)*256 + 4*q] = *(const f32x4*)&LB[rr*132 + 4*q];
    }
  }

  // ==== P3: SYRK A22' = A22 - L21*L21^T (stream A22, dots vs LDS L21, regs hold) ====
  float s1[16], s2[16];
  int R1 = 0, C1 = 0, R2 = 0, C2 = 0;
  bool v1 = (t < 528), v2 = (t < 16);
  if (v1) tri_decode(t, R1, C1);
  if (v2) tri_decode(512 + t, R2, C2);
  #pragma unroll
  for (int q = 0; q < 16; ++q){ s1[q] = 0.f; s2[q] = 0.f; }
  if (v1){
    for (int qc = 0; qc < 32; ++qc){
      f32x4 a0 = *(const f32x4*)&LB[(4*R1+0)*132 + 4*qc];
      f32x4 a1 = *(const f32x4*)&LB[(4*R1+1)*132 + 4*qc];
      f32x4 a2 = *(const f32x4*)&LB[(4*R1+2)*132 + 4*qc];
      f32x4 a3 = *(const f32x4*)&LB[(4*R1+3)*132 + 4*qc];
      f32x4 b0 = *(const f32x4*)&LB[(4*C1+0)*132 + 4*qc];
      f32x4 b1 = *(const f32x4*)&LB[(4*C1+1)*132 + 4*qc];
      f32x4 b2 = *(const f32x4*)&LB[(4*C1+2)*132 + 4*qc];
      f32x4 b3 = *(const f32x4*)&LB[(4*C1+3)*132 + 4*qc];
      s1[0]+=dot4(a0,b0);  s1[1]+=dot4(a0,b1);  s1[2]+=dot4(a0,b2);  s1[3]+=dot4(a0,b3);
      s1[4]+=dot4(a1,b0);  s1[5]+=dot4(a1,b1);  s1[6]+=dot4(a1,b2);  s1[7]+=dot4(a1,b3);
      s1[8]+=dot4(a2,b0);  s1[9]+=dot4(a2,b1);  s1[10]+=dot4(a2,b2); s1[11]+=dot4(a2,b3);
      s1[12]+=dot4(a3,b0); s1[13]+=dot4(a3,b1); s1[14]+=dot4(a3,b2); s1[15]+=dot4(a3,b3);
    }
    #pragma unroll
    for (int i2 = 0; i2 < 4; ++i2){
      f32x4 av = *(const f32x4*)&A[(size_t)(128+4*R1+i2)*256 + 128 + 4*C1];
      s1[i2*4+0] = av.x - s1[i2*4+0];
      s1[i2*4+1] = av.y - s1[i2*4+1];
      s1[i2*4+2] = av.z - s1[i2*4+2];
      s1[i2*4+3] = av.w - s1[i2*4+3];
    }
  }
  if (v2){
    for (int qc = 0; qc < 32; ++qc){
      f32x4 a0 = *(const f32x4*)&LB[(4*R2+0)*132 + 4*qc];
      f32x4 a1 = *(const f32x4*)&LB[(4*R2+1)*132 + 4*qc];
      f32x4 a2 = *(const f32x4*)&LB[(4*R2+2)*132 + 4*qc];
      f32x4 a3 = *(const f32x4*)&LB[(4*R2+3)*132 + 4*qc];
      f32x4 b0 = *(const f32x4*)&LB[(4*C2+0)*132 + 4*qc];
      f32x4 b1 = *(const f32x4*)&LB[(4*C2+1)*132 + 4*qc];
      f32x4 b2 = *(const f32x4*)&LB[(4*C2+2)*132 + 4*qc];
      f32x4 b3 = *(const f32x4*)&LB[(4*C2+3)*132 + 4*qc];
      s2[0]+=dot4(a0,b0);  s2[1]+=dot4(a0,b1);  s2[2]+=dot4(a0,b2);  s2[3]+=dot4(a0,b3);
      s2[4]+=dot4(a1,b0);  s2[5]+=dot4(a1,b1);  s2[6]+=dot4(a1,b2);  s2[7]+=dot4(a1,b3);
      s2[8]+=dot4(a2,b0);  s2[9]+=dot4(a2,b1);  s2[10]+=dot4(a2,b2); s2[11]+=dot4(a2,b3);
      s2[12]+=dot4(a3,b0); s2[13]+=dot4(a3,b1); s2[14]+=dot4(a3,b2); s2[15]+=dot4(a3,b3);
    }
    #pragma unroll
    for (int i2 = 0; i2 < 4; ++i2){
      f32x4 av = *(const f32x4*)&A[(size_t)(128+4*R2+i2)*256 + 128 + 4*C2];
      s2[i2*4+0] = av.x - s2[i2*4+0];
      s2[i2*4+1] = av.y - s2[i2*4+1];
      s2[i2*4+2] = av.z - s2[i2*4+2];
      s2[i2*4+3] = av.w - s2[i2*4+3];
    }
  }
  __syncthreads();     // all reads of LB (L21) complete
  if (v1){
    #pragma unroll
    for (int i2 = 0; i2 < 4; ++i2)
      #pragma unroll
      for (int jl = 0; jl < 4; ++jl)
        LB[(4*R1+i2)*132 + 4*C1+jl] = s1[i2*4+jl];
  }
  if (v2){
    #pragma unroll
    for (int i2 = 0; i2 < 4; ++i2)
      #pragma unroll
      for (int jl = 0; jl < 4; ++jl)
        LB[(4*R2+i2)*132 + 4*C2+jl] = s2[i2*4+jl];
  }
  __syncthreads();

  // ==== P4: factor A22' in LDS; write L22 ====
  factor128_v12(LB, t, ldacc);
  for (int i = t; i < 4096; i += 512){
    int r = i >> 5, q = i & 31;
    f32x4 v = *(const f32x4*)&LB[r*132 + 4*q];
    int cb = 4*q;
    v.x = (cb+0 <= r) ? v.x : 0.f;
    v.y = (cb+1 <= r) ? v.y : 0.f;
    v.z = (cb+2 <= r) ? v.z : 0.f;
    v.w = (cb+3 <= r) ? v.w : 0.f;
    *(f32x4*)&A[(size_t)(128+r)*256 + 128 + 4*q] = v;
  }
  // logdet: reduce wave0 lanes' per-column partials
  if (t < 32){
    float v = ldacc;
    #pragma unroll
    for (int m = 1; m < 32; m <<= 1) v += __shfl_xor(v, m);
    if (t == 0) logdet[l * 256 + c] = 2.0f * v;
  }
}

// ---------------- K3b: TRSM L1 W = L0 in place, column-per-thread; trp = ||W||_F^2 ----------------
__global__ __launch_bounds__(256) void k3b_trsm(float* __restrict__ sig, float* __restrict__ trp, int c0){
  __shared__ float L1blk[32 * 256];   // 32 KB
  __shared__ float redw[4];
  int t = threadIdx.x, b = blockIdx.x;
  int lane = t & 63, wav = t >> 6;
  const float* L1 = sig + (size_t)(b * 2 + 1) * MSZ;
  float* W = sig + (size_t)(b * 2) * MSZ;     // starts as L0, becomes W
  float tracc = 0.f;

  for (int RB = 0; RB < 8; ++RB){
    int r0 = RB * 32;
    __syncthreads();
    for (int i = t; i < 32 * 256; i += 256)
      L1blk[i] = L1[(size_t)(r0 + (i >> 8)) * 256 + (i & 255)];
    __syncthreads();

    float acc[32];
    #pragma unroll
    for (int r = 0; r < 32; ++r) acc[r] = W[(size_t)(r0 + r) * 256 + t];

    for (int p = 0; p < r0; p += 8){
      float wv[8];
      #pragma unroll
      for (int q = 0; q < 8; ++q) wv[q] = W[(size_t)(p + q) * 256 + t];
      #pragma unroll
      for (int r = 0; r < 32; ++r){
        const f32x4 La = *(const f32x4*)&L1blk[r * 256 + p];
        const f32x4 Lb = *(const f32x4*)&L1blk[r * 256 + p + 4];
        acc[r] -= La.x * wv[0] + La.y * wv[1] + La.z * wv[2] + La.w * wv[3]
                + Lb.x * wv[4] + Lb.y * wv[5] + Lb.z * wv[6] + Lb.w * wv[7];
      }
    }
    // in-block forward substitution (column-private, no barriers)
    #pragma unroll
    for (int rr = 0; rr < 32; ++rr){
      float v = acc[rr];
      #pragma unroll
      for (int q = 0; q < rr; ++q)
        v -= L1blk[rr * 256 + r0 + q] * acc[q];
      v /= L1blk[rr * 256 + r0 + rr];
      acc[rr] = v;
      tracc += v * v;
      W[(size_t)(r0 + rr) * 256 + t] = v;
    }
  }
  #pragma unroll
  for (int m = 1; m < 64; m <<= 1) tracc += __shfl_xor(tracc, m);
  if (lane == 0) redw[wav] = tracc;
  __syncthreads();
  if (t == 0) trp[c0 + b] = redw[0] + redw[1] + redw[2] + redw[3];
}

// ---------------- K3c: quad = ||L1^-1 d||^2; final per-channel kl ----------------
__global__ __launch_bounds__(64) void k3c_quad(const float* __restrict__ means, const float* __restrict__ sig,
    const float* __restrict__ trp, const float* __restrict__ logdet, float* __restrict__ klp, int c0){
  __shared__ float y[256];
  int t = threadIdx.x, b = blockIdx.x;
  int c = c0 + b;
  const float* L1 = sig + (size_t)(b * 2 + 1) * MSZ;
  const float* m1p = means + (size_t)(256 + c) * 256;
  const float* m0p = means + (size_t)c * 256;

  for (int r = 0; r < 256; ++r){
    float part = 0.f;
    for (int p = t; p < r; p += 64)
      part += L1[(size_t)r * 256 + p] * y[p];
    #pragma unroll
    for (int m = 1; m < 64; m <<= 1) part += __shfl_xor(part, m);
    if (t == 0)
      y[r] = ((m1p[r] - m0p[r]) - part) / L1[(size_t)r * 256 + r];
    __syncthreads();
  }
  float q = 0.f;
  #pragma unroll
  for (int i = 0; i < 4; ++i){ float v = y[t + 64 * i]; q += v * v; }
  #pragma unroll
  for (int m = 1; m < 64; m <<= 1) q += __shfl_xor(q, m);
  if (t == 0)
    klp[c] = 0.5f * (trp[c] + q - 256.0f + logdet[256 + c] - logdet[c]);
}

// ---------------- K4: final reduce + scale ----------------
__global__ void k4_final(const float* __restrict__ klp, const int* __restrict__ cnt, float* __restrict__ out){
  __shared__ float red[256];
  int t = threadIdx.x;
  red[t] = klp[t];
  __syncthreads();
  for (int s = 128; s > 0; s >>= 1){
    if (t < s) red[t] += red[t + s];
    __syncthreads();
  }
  if (t == 0){
    float n0 = (float)cnt[0], n1 = (float)cnt[1];
    out[0] = red[0] * n0 * n1 / 256.0f / 512.0f / 512.0f;
  }
}

extern "C" void kernel_launch(void* const* d_in, const int* in_sizes, int n_in,
                              void* d_out, int out_size, void* d_ws, size_t ws_size,
                              hipStream_t stream){
  (void)in_sizes; (void)n_in; (void)out_size;
  const float* mu  = (const float*)d_in[0];
  const float* cov = (const float*)d_in[1];
  const int*   lab = (const int*)d_in[2];
  float* out = (float*)d_out;
  char* ws = (char*)d_ws;
  // ws layout (bytes):
  // means  @ 0        (524288)   trp @ 524288 (1024)   klp @ 525312 (1024)
  // logdet @ 526336   (2048)     cnt @ 528384 (8)      idx @ 528392 (2048)
  // sig    @ 1048576  (ch*2 full 256x256 fp32 squares)
  float* means  = (float*)ws;
  float* trp    = (float*)(ws + 524288);
  float* klp    = (float*)(ws + 525312);
  float* logdet = (float*)(ws + 526336);
  int*   cnt    = (int*)  (ws + 528384);
  int*   idx    = (int*)  (ws + 528392);
  float* sig    = (float*)(ws + 1048576);
  const size_t base = 1048576;

  int ch = 0;
  if      (ws_size >= base + (size_t)256 * 2 * MSZ * 4) ch = 256;
  else if (ws_size >= base + (size_t)64  * 2 * MSZ * 4) ch = 64;
  else if (ws_size >= base + (size_t)16  * 2 * MSZ * 4) ch = 16;
  else if (ws_size >= base + (size_t)4   * 2 * MSZ * 4) ch = 4;
  else if (ws_size >= base + (size_t)1   * 2 * MSZ * 4) ch = 1;
  if (ch == 0){
    k_sentinel<<<1, 1, 0, stream>>>(out);
    return;
  }

  const int k3a_lds = 17952 * 4;   // 71808 B dynamic LDS
  (void)hipFuncSetAttribute((const void*)k3a_chol,
                            hipFuncAttributeMaxDynamicSharedMemorySize, k3a_lds);

  k0_partition<<<1, 512, 0, stream>>>(lab, cnt, idx);
  k1_means<<<256, 1024, 0, stream>>>(mu, lab, cnt, means);
  for (int c0 = 0; c0 < 256; c0 += ch){
    k2_gram<<<ch * 2, 512, 0, stream>>>(mu, cov, means, cnt, idx, sig, c0);
    k3a_chol<<<ch * 2, 512, k3a_lds, stream>>>(sig, logdet, c0);
    k3b_trsm<<<ch, 256, 0, stream>>>(sig, trp, c0);
    k3c_quad<<<ch, 64, 0, stream>>>(means, sig, trp, logdet, klp, c0);
  }
  k4_final<<<1, 256, 0, stream>>>(klp, cnt, out);
}

// Round 13
// 1108.582 us; speedup vs baseline: 1.9066x; 1.2479x over previous
//
#include <hip/hip_runtime.h>
#include <cmath>

typedef __attribute__((ext_vector_type(4))) float f32x4;
typedef __attribute__((ext_vector_type(8))) short bf16x8;

// matrices are full 256x256 fp32 squares; strict upper of each L is zeroed
#define MSZ 65536

__device__ __forceinline__ unsigned short f2bf(float f){
  unsigned u = __float_as_uint(f);
  unsigned r = (u + 0x7FFFu + ((u >> 16) & 1u)) >> 16;
  return (unsigned short)r;
}

__device__ __forceinline__ float dot4(f32x4 a, f32x4 b){
  return a.x*b.x + a.y*b.y + a.z*b.z + a.w*b.w;
}

__device__ __forceinline__ void tri_decode(int i, int& R, int& C){
  int Rv = (int)((sqrtf(8.f*(float)i + 1.f) - 1.f) * 0.5f);
  while ((Rv+1)*(Rv+2)/2 <= i) ++Rv;
  while (Rv*(Rv+1)/2 > i) --Rv;
  R = Rv; C = i - Rv*(Rv+1)/2;
}

__global__ void k_sentinel(float* __restrict__ out){ out[0] = 123456.0f; }

// ---------------- K0: partition batch indices by label ----------------
__global__ void k0_partition(const int* __restrict__ lab, int* __restrict__ cnt, int* __restrict__ idx){
  __shared__ int lcnt0[8], lcnt1[8];
  int t = threadIdx.x;              // 512 threads, 8 waves
  int w = t >> 6, lane = t & 63;
  int l = lab[t];
  unsigned long long m0 = __ballot(l == 0);
  unsigned long long bm = (lane == 0) ? 0ull : ((1ull << lane) - 1ull);
  int r0 = __popcll(m0 & bm);
  int r1 = __popcll((~m0) & bm);
  if (lane == 0){ lcnt0[w] = __popcll(m0); lcnt1[w] = 64 - __popcll(m0); }
  __syncthreads();
  int base0 = 0, base1 = 0, n0 = 0;
  #pragma unroll
  for (int i = 0; i < 8; ++i){
    if (i < w){ base0 += lcnt0[i]; base1 += lcnt1[i]; }
    n0 += lcnt0[i];
  }
  int pos = (l == 0) ? (base0 + r0) : (n0 + base1 + r1);
  idx[pos] = t;
  if (t == 0){ cnt[0] = n0; cnt[1] = 512 - n0; }
}

// ---------------- K1: per-label means ----------------
__global__ __launch_bounds__(1024) void k1_means(const float* __restrict__ x, const int* __restrict__ lab,
                                                 const int* __restrict__ cnt, float* __restrict__ means){
  __shared__ int labs[512];
  __shared__ float part[8][256];
  int t = threadIdx.x, c = blockIdx.x;
  if (t < 512) labs[t] = lab[t];
  __syncthreads();
  int k = t & 255, bq = t >> 8;
  float s0 = 0.f, s1 = 0.f;
  const float* xc = x + (size_t)c * 256 + k;
  for (int b = bq; b < 512; b += 4){
    float v = xc[(size_t)b * 65536];
    if (labs[b] == 0) s0 += v; else s1 += v;
  }
  part[bq*2+0][k] = s0;
  part[bq*2+1][k] = s1;
  __syncthreads();
  if (t < 256){
    float m0 = part[0][t] + part[2][t] + part[4][t] + part[6][t];
    float m1 = part[1][t] + part[3][t] + part[5][t] + part[7][t];
    float n0 = (float)cnt[0], n1 = (float)cnt[1];
    means[(size_t)c * 256 + t]         = m0 / fmaxf(n0, 1.f);
    means[(size_t)(256 + c) * 256 + t] = m1 / fmaxf(n1, 1.f);
  }
}

// ---------------- K2: per-(channel,label) Gram via MFMA -> Sigma full square, upper zeroed ----------------
__global__ __launch_bounds__(512) void k2_gram(const float* __restrict__ x, const float* __restrict__ cov,
    const float* __restrict__ means, const int* __restrict__ cnt, const int* __restrict__ idx,
    float* __restrict__ sig, int c0){
  __shared__ uint4 XT4[1280];      // 256 k-rows x (4 uint4 data + 1 pad uint4)
  __shared__ float mlds[256];
  int t = threadIdx.x;
  int bid = blockIdx.x;
  int l = bid & 1, c = c0 + (bid >> 1);
  int n0 = cnt[0], n1 = cnt[1];
  int n = l ? n1 : n0;
  int start = l ? n0 : 0;
  if (t < 256) mlds[t] = means[(size_t)(l * 256 + c) * 256 + t];

  f32x4 acc[8][4];
  #pragma unroll
  for (int i = 0; i < 8; ++i)
    #pragma unroll
    for (int jn = 0; jn < 4; ++jn){ f32x4 z; z.x = 0.f; z.y = 0.f; z.z = 0.f; z.w = 0.f; acc[i][jn] = z; }

  int lane = t & 63, wav = t >> 6;
  int wr = wav >> 2, wc = wav & 3;
  int lrow = lane & 15, lhalf = lane >> 4;   // lhalf in [0,4)
  int kq = t & 255, bh = t >> 8;
  int nst = (n + 31) >> 5;

  for (int s = 0; s < nst; ++s){
    __syncthreads();
    unsigned pk[8];
    #pragma unroll
    for (int m = 0; m < 8; ++m){
      int b0 = s * 32 + bh * 16 + 2 * m;
      float v0 = 0.f, v1 = 0.f;
      if (b0 < n)     v0 = x[((size_t)idx[start + b0] * 256 + c) * 256 + kq];
      if (b0 + 1 < n) v1 = x[((size_t)idx[start + b0 + 1] * 256 + c) * 256 + kq];
      pk[m] = (unsigned)f2bf(v0) | ((unsigned)f2bf(v1) << 16);
    }
    XT4[kq * 5 + bh * 2 + 0] = make_uint4(pk[0], pk[1], pk[2], pk[3]);
    XT4[kq * 5 + bh * 2 + 1] = make_uint4(pk[4], pk[5], pk[6], pk[7]);
    __syncthreads();
    bf16x8 af[8], bfr[4];
    #pragma unroll
    for (int i = 0; i < 8; ++i){
      int T = wr * 8 + i;
      af[i] = *reinterpret_cast<const bf16x8*>(&XT4[(T * 16 + lrow) * 5 + lhalf]);
    }
    #pragma unroll
    for (int jn = 0; jn < 4; ++jn){
      int T = wc * 4 + jn;
      bfr[jn] = *reinterpret_cast<const bf16x8*>(&XT4[(T * 16 + lrow) * 5 + lhalf]);
    }
    #pragma unroll
    for (int i = 0; i < 8; ++i)
      #pragma unroll
      for (int jn = 0; jn < 4; ++jn)
        acc[i][jn] = __builtin_amdgcn_mfma_f32_16x16x32_bf16(af[i], bfr[jn], acc[i][jn], 0, 0, 0);
  }
  __syncthreads();

  float invn = 1.0f / fmaxf((float)n, 1.0f);
  float* sigm = sig + (size_t)bid * MSZ;
  #pragma unroll
  for (int i = 0; i < 8; ++i){
    int Rb = (wr * 8 + i) * 16 + lhalf * 4;
    #pragma unroll
    for (int jn = 0; jn < 4; ++jn){
      int Cc = (wc * 4 + jn) * 16 + lrow;
      #pragma unroll
      for (int r = 0; r < 4; ++r){
        int R = Rb + r;
        float v = acc[i][jn][r] * invn + cov[R * 256 + Cc] - mlds[R] * mlds[Cc];
        sigm[R * 256 + Cc] = (Cc <= R) ? v : 0.0f;   // zero strict upper
      }
    }
  }
}

// ---------------- K3a helper: in-LDS 128x128 right-looking Cholesky ----------------
// LB: 128 x (stride 132). Diag: 4x4-blocked (8 sub-steps; named scalars, broadcast
// reads, unroll-4 rank-4 row updates -- no long serial LDS chains, no reg arrays).
// Panel: per-row register forward substitution (r12-verified). No Linv anywhere.
__device__ void factor128_v13(float* __restrict__ LB, int t, float& ldacc){
  for (int kb = 0; kb < 4; ++kb){
    int j0 = kb * 32;
    // ---- (a) wave0: 4x4-blocked chol of 32x32 diag block
    if (t < 64){
      #pragma unroll 1
      for (int s8 = 0; s8 < 8; ++s8){
        int js = j0 + 4*s8;
        // (i) all lanes redundantly compute the 4x4 chol (broadcast LDS reads)
        float a00 = LB[(js+0)*132 + js+0];
        float a10 = LB[(js+1)*132 + js+0], a11 = LB[(js+1)*132 + js+1];
        float a20 = LB[(js+2)*132 + js+0], a21 = LB[(js+2)*132 + js+1], a22 = LB[(js+2)*132 + js+2];
        float a30 = LB[(js+3)*132 + js+0], a31 = LB[(js+3)*132 + js+1], a32 = LB[(js+3)*132 + js+2], a33 = LB[(js+3)*132 + js+3];
        float l00 = sqrtf(a00);
        float i00 = 1.0f / l00;
        float l10 = a10 * i00, l20 = a20 * i00, l30 = a30 * i00;
        float l11 = sqrtf(a11 - l10*l10);
        float i11 = 1.0f / l11;
        float l21 = (a21 - l20*l10) * i11, l31 = (a31 - l30*l10) * i11;
        float l22 = sqrtf(a22 - l20*l20 - l21*l21);
        float i22 = 1.0f / l22;
        float l32 = (a32 - l30*l20 - l31*l21) * i22;
        float l33 = sqrtf(a33 - l30*l30 - l31*l31 - l32*l32);
        float i33 = 1.0f / l33;
        if (t == 0){
          LB[(js+0)*132 + js+0] = l00;
          LB[(js+1)*132 + js+0] = l10; LB[(js+1)*132 + js+1] = l11;
          LB[(js+2)*132 + js+0] = l20; LB[(js+2)*132 + js+1] = l21; LB[(js+2)*132 + js+2] = l22;
          LB[(js+3)*132 + js+0] = l30; LB[(js+3)*132 + js+1] = l31; LB[(js+3)*132 + js+2] = l32; LB[(js+3)*132 + js+3] = l33;
          ldacc += logf(l00) + logf(l11) + logf(l22) + logf(l33);
        }
        // (ii) in-block panel rows: lane t owns row r = js+4+t
        int cnt2 = 28 - 4*s8;
        int r = js + 4 + t;
        if (t < cnt2){
          float w0 = LB[r*132 + js+0], w1 = LB[r*132 + js+1], w2 = LB[r*132 + js+2], w3 = LB[r*132 + js+3];
          w0 = w0 * i00;
          w1 = (w1 - l10*w0) * i11;
          w2 = (w2 - l20*w0 - l21*w1) * i22;
          w3 = (w3 - l30*w0 - l31*w1 - l32*w2) * i33;
          LB[r*132 + js+0] = w0; LB[r*132 + js+1] = w1; LB[r*132 + js+2] = w2; LB[r*132 + js+3] = w3;
          // (iii) rank-4 update of own row r, cols js+4..r (independent iters)
          #pragma unroll 4
          for (int cq2 = js + 4; cq2 <= r; ++cq2){
            f32x4 Lc = *(const f32x4*)&LB[cq2*132 + js];
            LB[r*132 + cq2] -= w0*Lc.x + w1*Lc.y + w2*Lc.z + w3*Lc.w;
          }
        }
      }
    }
    __syncthreads();
    int nr = 96 - j0;              // panel rows below diag
    if (nr > 0){
      // ---- (b) panel: per-row forward substitution (register w, broadcast LDS reads)
      if (t < nr){
        int row = j0 + 32 + t;
        float w[32];
        #pragma unroll
        for (int q = 0; q < 8; ++q){
          f32x4 v = *(const f32x4*)&LB[row*132 + j0 + 4*q];
          w[4*q] = v.x; w[4*q+1] = v.y; w[4*q+2] = v.z; w[4*q+3] = v.w;
        }
        #pragma unroll
        for (int cc = 0; cc < 32; ++cc){
          float s = w[cc];
          #pragma unroll
          for (int p = 0; p < cc; ++p) s -= LB[(j0+cc)*132 + j0 + p] * w[p];
          w[cc] = s / LB[(j0+cc)*132 + j0 + cc];
        }
        #pragma unroll
        for (int q = 0; q < 8; ++q){
          f32x4 v; v.x = w[4*q]; v.y = w[4*q+1]; v.z = w[4*q+2]; v.w = w[4*q+3];
          *(f32x4*)&LB[row*132 + j0 + 4*q] = v;
        }
      }
      __syncthreads();
      // ---- (c) trailing rank-32 update: 4x4 tiles over lower tile-triangle
      int nt = nr >> 2;
      int Tt = nt*(nt+1)/2;        // 300 / 136 / 36
      if (t < Tt){
        int R, C; tri_decode(t, R, C);
        int rb = j0+32+4*R, cb = j0+32+4*C;
        float s[16];
        #pragma unroll
        for (int q = 0; q < 16; ++q) s[q] = 0.f;
        #pragma unroll 4
        for (int qc = 0; qc < 8; ++qc){
          f32x4 a0 = *(const f32x4*)&LB[(rb+0)*132 + j0 + 4*qc];
          f32x4 a1 = *(const f32x4*)&LB[(rb+1)*132 + j0 + 4*qc];
          f32x4 a2 = *(const f32x4*)&LB[(rb+2)*132 + j0 + 4*qc];
          f32x4 a3 = *(const f32x4*)&LB[(rb+3)*132 + j0 + 4*qc];
          f32x4 b0 = *(const f32x4*)&LB[(cb+0)*132 + j0 + 4*qc];
          f32x4 b1 = *(const f32x4*)&LB[(cb+1)*132 + j0 + 4*qc];
          f32x4 b2 = *(const f32x4*)&LB[(cb+2)*132 + j0 + 4*qc];
          f32x4 b3 = *(const f32x4*)&LB[(cb+3)*132 + j0 + 4*qc];
          s[0]+=dot4(a0,b0);  s[1]+=dot4(a0,b1);  s[2]+=dot4(a0,b2);  s[3]+=dot4(a0,b3);
          s[4]+=dot4(a1,b0);  s[5]+=dot4(a1,b1);  s[6]+=dot4(a1,b2);  s[7]+=dot4(a1,b3);
          s[8]+=dot4(a2,b0);  s[9]+=dot4(a2,b1);  s[10]+=dot4(a2,b2); s[11]+=dot4(a2,b3);
          s[12]+=dot4(a3,b0); s[13]+=dot4(a3,b1); s[14]+=dot4(a3,b2); s[15]+=dot4(a3,b3);
        }
        #pragma unroll
        for (int i2 = 0; i2 < 4; ++i2)
          #pragma unroll
          for (int jl = 0; jl < 4; ++jl)
            LB[(rb+i2)*132 + cb+jl] -= s[i2*4+jl];
      }
    }
    __syncthreads();
  }
}

// ---------------- K3a: two-level Schur Cholesky, 71.8 KB dynamic LDS ----------------
// P1 chol(A11) in LDS; P2 TRSM L21 (L11 blocks staged into LT, per-row substitution);
// P3 SYRK streamed from global vs LDS L21; P4 chol(A22').
__global__ __launch_bounds__(512) void k3a_chol(float* __restrict__ sig, float* __restrict__ logdet, int c0){
  extern __shared__ float smem[];
  float* LB = smem;                 // 128*132 = 16896 floats
  float* LT = smem + 16896;         // 1056 floats (staged 32x32 L blocks, stride 33)
  int t = threadIdx.x;
  int bid = blockIdx.x;
  int l = bid & 1, c = c0 + (bid >> 1);
  float* A = sig + (size_t)bid * MSZ;
  float ldacc = 0.f;

  // ==== P1: load A11, factor in LDS, write L11 ====
  for (int i = t; i < 4096; i += 512){
    int r = i >> 5, q = i & 31;
    *(f32x4*)&LB[r*132 + 4*q] = *(const f32x4*)&A[(size_t)r*256 + 4*q];
  }
  __syncthreads();
  factor128_v13(LB, t, ldacc);
  for (int i = t; i < 4096; i += 512){
    int r = i >> 5, q = i & 31;
    f32x4 v = *(const f32x4*)&LB[r*132 + 4*q];
    int cb = 4*q;
    v.x = (cb+0 <= r) ? v.x : 0.f;
    v.y = (cb+1 <= r) ? v.y : 0.f;
    v.z = (cb+2 <= r) ? v.z : 0.f;
    v.w = (cb+3 <= r) ? v.w : 0.f;
    *(f32x4*)&A[(size_t)r*256 + 4*q] = v;
  }
  __syncthreads();

  // ==== P2: TRSM L21 = A21 * L11^-T; W in LB; L11 blocks staged from global ====
  {
    int r2 = t >> 2, g = t & 3;
    for (int kb = 0; kb < 4; ++kb){
      f32x4 v0 = *(const f32x4*)&A[(size_t)(128+r2)*256 + 32*kb + 8*g];
      f32x4 v1 = *(const f32x4*)&A[(size_t)(128+r2)*256 + 32*kb + 8*g + 4];
      float accv[8] = {v0.x, v0.y, v0.z, v0.w, v1.x, v1.y, v1.z, v1.w};
      for (int p = 0; p < kb; ++p){
        __syncthreads();   // prior LT readers done
        for (int i = t; i < 1024; i += 512){
          int j = i & 31, q = i >> 5;
          LT[q*33 + j] = A[(size_t)(32*kb + j)*256 + 32*p + q];   // LT[q][j] = L11[32kb+j][32p+q]
        }
        __syncthreads();
        f32x4 wv[8];
        #pragma unroll
        for (int q = 0; q < 8; ++q) wv[q] = *(const f32x4*)&LB[r2*132 + 32*p + 4*q];
        #pragma unroll
        for (int q4 = 0; q4 < 8; ++q4)
          #pragma unroll
          for (int jl = 0; jl < 8; ++jl)
            accv[jl] -= wv[q4].x * LT[(4*q4+0)*33 + 8*g+jl]
                      + wv[q4].y * LT[(4*q4+1)*33 + 8*g+jl]
                      + wv[q4].z * LT[(4*q4+2)*33 + 8*g+jl]
                      + wv[q4].w * LT[(4*q4+3)*33 + 8*g+jl];
      }
      #pragma unroll
      for (int jl = 0; jl < 8; ++jl) LB[r2*132 + 32*kb + 8*g + jl] = accv[jl];
      __syncthreads();   // LB writes visible; prior LT readers done
      // stage diag L block of column kb
      for (int i = t; i < 1024; i += 512){
        int cc = i >> 5, p = i & 31;
        LT[cc*33 + p] = A[(size_t)(32*kb + cc)*256 + 32*kb + p];  // L[cc][p]
      }
      __syncthreads();
      if (t < 128){      // per-row substitution vs diag block
        float w[32];
        #pragma unroll
        for (int q = 0; q < 8; ++q){
          f32x4 v = *(const f32x4*)&LB[t*132 + 32*kb + 4*q];
          w[4*q] = v.x; w[4*q+1] = v.y; w[4*q+2] = v.z; w[4*q+3] = v.w;
        }
        #pragma unroll
        for (int cc = 0; cc < 32; ++cc){
          float s = w[cc];
          #pragma unroll
          for (int p = 0; p < cc; ++p) s -= LT[cc*33 + p] * w[p];
          w[cc] = s / LT[cc*33 + cc];
        }
        #pragma unroll
        for (int q = 0; q < 8; ++q){
          f32x4 v; v.x = w[4*q]; v.y = w[4*q+1]; v.z = w[4*q+2]; v.w = w[4*q+3];
          *(f32x4*)&LB[t*132 + 32*kb + 4*q] = v;
        }
      }
      __syncthreads();
    }
    // write L21 (dense)
    for (int i = t; i < 4096; i += 512){
      int rr = i >> 5, q = i & 31;
      *(f32x4*)&A[(size_t)(128+rr)*256 + 4*q] = *(const f32x4*)&LB[rr*132 + 4*q];
    }
  }

  // ==== P3: SYRK A22' = A22 - L21*L21^T (stream A22, dots vs LDS L21, regs hold) ====
  float s1[16], s2[16];
  int R1 = 0, C1 = 0, R2 = 0, C2 = 0;
  bool v1 = (t < 528), v2 = (t < 16);
  if (v1) tri_decode(t, R1, C1);
  if (v2) tri_decode(512 + t, R2, C2);
  #pragma unroll
  for (int q = 0; q < 16; ++q){ s1[q] = 0.f; s2[q] = 0.f; }
  if (v1){
    for (int qc = 0; qc < 32; ++qc){
      f32x4 a0 = *(const f32x4*)&LB[(4*R1+0)*132 + 4*qc];
      f32x4 a1 = *(const f32x4*)&LB[(4*R1+1)*132 + 4*qc];
      f32x4 a2 = *(const f32x4*)&LB[(4*R1+2)*132 + 4*qc];
      f32x4 a3 = *(const f32x4*)&LB[(4*R1+3)*132 + 4*qc];
      f32x4 b0 = *(const f32x4*)&LB[(4*C1+0)*132 + 4*qc];
      f32x4 b1 = *(const f32x4*)&LB[(4*C1+1)*132 + 4*qc];
      f32x4 b2 = *(const f32x4*)&LB[(4*C1+2)*132 + 4*qc];
      f32x4 b3 = *(const f32x4*)&LB[(4*C1+3)*132 + 4*qc];
      s1[0]+=dot4(a0,b0);  s1[1]+=dot4(a0,b1);  s1[2]+=dot4(a0,b2);  s1[3]+=dot4(a0,b3);
      s1[4]+=dot4(a1,b0);  s1[5]+=dot4(a1,b1);  s1[6]+=dot4(a1,b2);  s1[7]+=dot4(a1,b3);
      s1[8]+=dot4(a2,b0);  s1[9]+=dot4(a2,b1);  s1[10]+=dot4(a2,b2); s1[11]+=dot4(a2,b3);
      s1[12]+=dot4(a3,b0); s1[13]+=dot4(a3,b1); s1[14]+=dot4(a3,b2); s1[15]+=dot4(a3,b3);
    }
    #pragma unroll
    for (int i2 = 0; i2 < 4; ++i2){
      f32x4 av = *(const f32x4*)&A[(size_t)(128+4*R1+i2)*256 + 128 + 4*C1];
      s1[i2*4+0] = av.x - s1[i2*4+0];
      s1[i2*4+1] = av.y - s1[i2*4+1];
      s1[i2*4+2] = av.z - s1[i2*4+2];
      s1[i2*4+3] = av.w - s1[i2*4+3];
    }
  }
  if (v2){
    for (int qc = 0; qc < 32; ++qc){
      f32x4 a0 = *(const f32x4*)&LB[(4*R2+0)*132 + 4*qc];
      f32x4 a1 = *(const f32x4*)&LB[(4*R2+1)*132 + 4*qc];
      f32x4 a2 = *(const f32x4*)&LB[(4*R2+2)*132 + 4*qc];
      f32x4 a3 = *(const f32x4*)&LB[(4*R2+3)*132 + 4*qc];
      f32x4 b0 = *(const f32x4*)&LB[(4*C2+0)*132 + 4*qc];
      f32x4 b1 = *(const f32x4*)&LB[(4*C2+1)*132 + 4*qc];
      f32x4 b2 = *(const f32x4*)&LB[(4*C2+2)*132 + 4*qc];
      f32x4 b3 = *(const f32x4*)&LB[(4*C2+3)*132 + 4*qc];
      s2[0]+=dot4(a0,b0);  s2[1]+=dot4(a0,b1);  s2[2]+=dot4(a0,b2);  s2[3]+=dot4(a0,b3);
      s2[4]+=dot4(a1,b0);  s2[5]+=dot4(a1,b1);  s2[6]+=dot4(a1,b2);  s2[7]+=dot4(a1,b3);
      s2[8]+=dot4(a2,b0);  s2[9]+=dot4(a2,b1);  s2[10]+=dot4(a2,b2); s2[11]+=dot4(a2,b3);
      s2[12]+=dot4(a3,b0); s2[13]+=dot4(a3,b1); s2[14]+=dot4(a3,b2); s2[15]+=dot4(a3,b3);
    }
    #pragma unroll
    for (int i2 = 0; i2 < 4; ++i2){
      f32x4 av = *(const f32x4*)&A[(size_t)(128+4*R2+i2)*256 + 128 + 4*C2];
      s2[i2*4+0] = av.x - s2[i2*4+0];
      s2[i2*4+1] = av.y - s2[i2*4+1];
      s2[i2*4+2] = av.z - s2[i2*4+2];
      s2[i2*4+3] = av.w - s2[i2*4+3];
    }
  }
  __syncthreads();     // all reads of LB (L21) complete
  if (v1){
    #pragma unroll
    for (int i2 = 0; i2 < 4; ++i2)
      #pragma unroll
      for (int jl = 0; jl < 4; ++jl)
        LB[(4*R1+i2)*132 + 4*C1+jl] = s1[i2*4+jl];
  }
  if (v2){
    #pragma unroll
    for (int i2 = 0; i2 < 4; ++i2)
      #pragma unroll
      for (int jl = 0; jl < 4; ++jl)
        LB[(4*R2+i2)*132 + 4*C2+jl] = s2[i2*4+jl];
  }
  __syncthreads();

  // ==== P4: factor A22' in LDS; write L22 ====
  factor128_v13(LB, t, ldacc);
  for (int i = t; i < 4096; i += 512){
    int r = i >> 5, q = i & 31;
    f32x4 v = *(const f32x4*)&LB[r*132 + 4*q];
    int cb = 4*q;
    v.x = (cb+0 <= r) ? v.x : 0.f;
    v.y = (cb+1 <= r) ? v.y : 0.f;
    v.z = (cb+2 <= r) ? v.z : 0.f;
    v.w = (cb+3 <= r) ? v.w : 0.f;
    *(f32x4*)&A[(size_t)(128+r)*256 + 128 + 4*q] = v;
  }
  // logdet: reduce wave0 lanes' partials (lane 0 holds the full sum)
  if (t < 32){
    float v = ldacc;
    #pragma unroll
    for (int m = 1; m < 32; m <<= 1) v += __shfl_xor(v, m);
    if (t == 0) logdet[l * 256 + c] = 2.0f * v;
  }
}

// ---------------- K3b: TRSM L1 W = L0 in place, column-per-thread; trp = ||W||_F^2 ----------------
__global__ __launch_bounds__(256) void k3b_trsm(float* __restrict__ sig, float* __restrict__ trp, int c0){
  __shared__ float L1blk[32 * 256];   // 32 KB
  __shared__ float redw[4];
  int t = threadIdx.x, b = blockIdx.x;
  int lane = t & 63, wav = t >> 6;
  const float* L1 = sig + (size_t)(b * 2 + 1) * MSZ;
  float* W = sig + (size_t)(b * 2) * MSZ;     // starts as L0, becomes W
  float tracc = 0.f;

  for (int RB = 0; RB < 8; ++RB){
    int r0 = RB * 32;
    __syncthreads();
    for (int i = t; i < 32 * 256; i += 256)
      L1blk[i] = L1[(size_t)(r0 + (i >> 8)) * 256 + (i & 255)];
    __syncthreads();

    float acc[32];
    #pragma unroll
    for (int r = 0; r < 32; ++r) acc[r] = W[(size_t)(r0 + r) * 256 + t];

    for (int p = 0; p < r0; p += 8){
      float wv[8];
      #pragma unroll
      for (int q = 0; q < 8; ++q) wv[q] = W[(size_t)(p + q) * 256 + t];
      #pragma unroll
      for (int r = 0; r < 32; ++r){
        const f32x4 La = *(const f32x4*)&L1blk[r * 256 + p];
        const f32x4 Lb = *(const f32x4*)&L1blk[r * 256 + p + 4];
        acc[r] -= La.x * wv[0] + La.y * wv[1] + La.z * wv[2] + La.w * wv[3]
                + Lb.x * wv[4] + Lb.y * wv[5] + Lb.z * wv[6] + Lb.w * wv[7];
      }
    }
    // in-block forward substitution (column-private, no barriers)
    #pragma unroll
    for (int rr = 0; rr < 32; ++rr){
      float v = acc[rr];
      #pragma unroll
      for (int q = 0; q < rr; ++q)
        v -= L1blk[rr * 256 + r0 + q] * acc[q];
      v /= L1blk[rr * 256 + r0 + rr];
      acc[rr] = v;
      tracc += v * v;
      W[(size_t)(r0 + rr) * 256 + t] = v;
    }
  }
  #pragma unroll
  for (int m = 1; m < 64; m <<= 1) tracc += __shfl_xor(tracc, m);
  if (lane == 0) redw[wav] = tracc;
  __syncthreads();
  if (t == 0) trp[c0 + b] = redw[0] + redw[1] + redw[2] + redw[3];
}

// ---------------- K3c: quad = ||L1^-1 d||^2; final per-channel kl ----------------
__global__ __launch_bounds__(64) void k3c_quad(const float* __restrict__ means, const float* __restrict__ sig,
    const float* __restrict__ trp, const float* __restrict__ logdet, float* __restrict__ klp, int c0){
  __shared__ float y[256];
  int t = threadIdx.x, b = blockIdx.x;
  int c = c0 + b;
  const float* L1 = sig + (size_t)(b * 2 + 1) * MSZ;
  const float* m1p = means + (size_t)(256 + c) * 256;
  const float* m0p = means + (size_t)c * 256;

  for (int r = 0; r < 256; ++r){
    float part = 0.f;
    for (int p = t; p < r; p += 64)
      part += L1[(size_t)r * 256 + p] * y[p];
    #pragma unroll
    for (int m = 1; m < 64; m <<= 1) part += __shfl_xor(part, m);
    if (t == 0)
      y[r] = ((m1p[r] - m0p[r]) - part) / L1[(size_t)r * 256 + r];
    __syncthreads();
  }
  float q = 0.f;
  #pragma unroll
  for (int i = 0; i < 4; ++i){ float v = y[t + 64 * i]; q += v * v; }
  #pragma unroll
  for (int m = 1; m < 64; m <<= 1) q += __shfl_xor(q, m);
  if (t == 0)
    klp[c] = 0.5f * (trp[c] + q - 256.0f + logdet[256 + c] - logdet[c]);
}

// ---------------- K4: final reduce + scale ----------------
__global__ void k4_final(const float* __restrict__ klp, const int* __restrict__ cnt, float* __restrict__ out){
  __shared__ float red[256];
  int t = threadIdx.x;
  red[t] = klp[t];
  __syncthreads();
  for (int s = 128; s > 0; s >>= 1){
    if (t < s) red[t] += red[t + s];
    __syncthreads();
  }
  if (t == 0){
    float n0 = (float)cnt[0], n1 = (float)cnt[1];
    out[0] = red[0] * n0 * n1 / 256.0f / 512.0f / 512.0f;
  }
}

extern "C" void kernel_launch(void* const* d_in, const int* in_sizes, int n_in,
                              void* d_out, int out_size, void* d_ws, size_t ws_size,
                              hipStream_t stream){
  (void)in_sizes; (void)n_in; (void)out_size;
  const float* mu  = (const float*)d_in[0];
  const float* cov = (const float*)d_in[1];
  const int*   lab = (const int*)d_in[2];
  float* out = (float*)d_out;
  char* ws = (char*)d_ws;
  // ws layout (bytes):
  // means  @ 0        (524288)   trp @ 524288 (1024)   klp @ 525312 (1024)
  // logdet @ 526336   (2048)     cnt @ 528384 (8)      idx @ 528392 (2048)
  // sig    @ 1048576  (ch*2 full 256x256 fp32 squares)
  float* means  = (float*)ws;
  float* trp    = (float*)(ws + 524288);
  float* klp    = (float*)(ws + 525312);
  float* logdet = (float*)(ws + 526336);
  int*   cnt    = (int*)  (ws + 528384);
  int*   idx    = (int*)  (ws + 528392);
  float* sig    = (float*)(ws + 1048576);
  const size_t base = 1048576;

  int ch = 0;
  if      (ws_size >= base + (size_t)256 * 2 * MSZ * 4) ch = 256;
  else if (ws_size >= base + (size_t)64  * 2 * MSZ * 4) ch = 64;
  else if (ws_size >= base + (size_t)16  * 2 * MSZ * 4) ch = 16;
  else if (ws_size >= base + (size_t)4   * 2 * MSZ * 4) ch = 4;
  else if (ws_size >= base + (size_t)1   * 2 * MSZ * 4) ch = 1;
  if (ch == 0){
    k_sentinel<<<1, 1, 0, stream>>>(out);
    return;
  }

  const int k3a_lds = 17952 * 4;   // 71808 B dynamic LDS
  (void)hipFuncSetAttribute((const void*)k3a_chol,
                            hipFuncAttributeMaxDynamicSharedMemorySize, k3a_lds);

  k0_partition<<<1, 512, 0, stream>>>(lab, cnt, idx);
  k1_means<<<256, 1024, 0, stream>>>(mu, lab, cnt, means);
  for (int c0 = 0; c0 < 256; c0 += ch){
    k2_gram<<<ch * 2, 512, 0, stream>>>(mu, cov, means, cnt, idx, sig, c0);
    k3a_chol<<<ch * 2, 512, k3a_lds, stream>>>(sig, logdet, c0);
    k3b_trsm<<<ch, 256, 0, stream>>>(sig, trp, c0);
    k3c_quad<<<ch, 64, 0, stream>>>(means, sig, trp, logdet, klp, c0);
  }
  k4_final<<<1, 256, 0, stream>>>(klp, cnt, out);
}

// Round 14
// 929.333 us; speedup vs baseline: 2.2744x; 1.1929x over previous
//
#include <hip/hip_runtime.h>
#include <cmath>

typedef __attribute__((ext_vector_type(4))) float f32x4;
typedef __attribute__((ext_vector_type(8))) short bf16x8;

// matrices are full 256x256 fp32 squares; strict upper of each L is zeroed
#define MSZ 65536

__device__ __forceinline__ unsigned short f2bf(float f){
  unsigned u = __float_as_uint(f);
  unsigned r = (u + 0x7FFFu + ((u >> 16) & 1u)) >> 16;
  return (unsigned short)r;
}

__device__ __forceinline__ float dot4(f32x4 a, f32x4 b){
  return a.x*b.x + a.y*b.y + a.z*b.z + a.w*b.w;
}

__device__ __forceinline__ void tri_decode(int i, int& R, int& C){
  int Rv = (int)((sqrtf(8.f*(float)i + 1.f) - 1.f) * 0.5f);
  while ((Rv+1)*(Rv+2)/2 <= i) ++Rv;
  while (Rv*(Rv+1)/2 > i) --Rv;
  R = Rv; C = i - Rv*(Rv+1)/2;
}

__global__ void k_sentinel(float* __restrict__ out){ out[0] = 123456.0f; }

// ---------------- K0: partition batch indices by label ----------------
__global__ void k0_partition(const int* __restrict__ lab, int* __restrict__ cnt, int* __restrict__ idx){
  __shared__ int lcnt0[8], lcnt1[8];
  int t = threadIdx.x;              // 512 threads, 8 waves
  int w = t >> 6, lane = t & 63;
  int l = lab[t];
  unsigned long long m0 = __ballot(l == 0);
  unsigned long long bm = (lane == 0) ? 0ull : ((1ull << lane) - 1ull);
  int r0 = __popcll(m0 & bm);
  int r1 = __popcll((~m0) & bm);
  if (lane == 0){ lcnt0[w] = __popcll(m0); lcnt1[w] = 64 - __popcll(m0); }
  __syncthreads();
  int base0 = 0, base1 = 0, n0 = 0;
  #pragma unroll
  for (int i = 0; i < 8; ++i){
    if (i < w){ base0 += lcnt0[i]; base1 += lcnt1[i]; }
    n0 += lcnt0[i];
  }
  int pos = (l == 0) ? (base0 + r0) : (n0 + base1 + r1);
  idx[pos] = t;
  if (t == 0){ cnt[0] = n0; cnt[1] = 512 - n0; }
}

// ---------------- K1: per-label means ----------------
__global__ __launch_bounds__(1024) void k1_means(const float* __restrict__ x, const int* __restrict__ lab,
                                                 const int* __restrict__ cnt, float* __restrict__ means){
  __shared__ int labs[512];
  __shared__ float part[8][256];
  int t = threadIdx.x, c = blockIdx.x;
  if (t < 512) labs[t] = lab[t];
  __syncthreads();
  int k = t & 255, bq = t >> 8;
  float s0 = 0.f, s1 = 0.f;
  const float* xc = x + (size_t)c * 256 + k;
  for (int b = bq; b < 512; b += 4){
    float v = xc[(size_t)b * 65536];
    if (labs[b] == 0) s0 += v; else s1 += v;
  }
  part[bq*2+0][k] = s0;
  part[bq*2+1][k] = s1;
  __syncthreads();
  if (t < 256){
    float m0 = part[0][t] + part[2][t] + part[4][t] + part[6][t];
    float m1 = part[1][t] + part[3][t] + part[5][t] + part[7][t];
    float n0 = (float)cnt[0], n1 = (float)cnt[1];
    means[(size_t)c * 256 + t]         = m0 / fmaxf(n0, 1.f);
    means[(size_t)(256 + c) * 256 + t] = m1 / fmaxf(n1, 1.f);
  }
}

// ---------------- K2: per-(channel,label) Gram via MFMA -> Sigma full square, upper zeroed ----------------
__global__ __launch_bounds__(512) void k2_gram(const float* __restrict__ x, const float* __restrict__ cov,
    const float* __restrict__ means, const int* __restrict__ cnt, const int* __restrict__ idx,
    float* __restrict__ sig, int c0){
  __shared__ uint4 XT4[1280];      // 256 k-rows x (4 uint4 data + 1 pad uint4)
  __shared__ float mlds[256];
  int t = threadIdx.x;
  int bid = blockIdx.x;
  int l = bid & 1, c = c0 + (bid >> 1);
  int n0 = cnt[0], n1 = cnt[1];
  int n = l ? n1 : n0;
  int start = l ? n0 : 0;
  if (t < 256) mlds[t] = means[(size_t)(l * 256 + c) * 256 + t];

  f32x4 acc[8][4];
  #pragma unroll
  for (int i = 0; i < 8; ++i)
    #pragma unroll
    for (int jn = 0; jn < 4; ++jn){ f32x4 z; z.x = 0.f; z.y = 0.f; z.z = 0.f; z.w = 0.f; acc[i][jn] = z; }

  int lane = t & 63, wav = t >> 6;
  int wr = wav >> 2, wc = wav & 3;
  int lrow = lane & 15, lhalf = lane >> 4;   // lhalf in [0,4)
  int kq = t & 255, bh = t >> 8;
  int nst = (n + 31) >> 5;

  for (int s = 0; s < nst; ++s){
    __syncthreads();
    unsigned pk[8];
    #pragma unroll
    for (int m = 0; m < 8; ++m){
      int b0 = s * 32 + bh * 16 + 2 * m;
      float v0 = 0.f, v1 = 0.f;
      if (b0 < n)     v0 = x[((size_t)idx[start + b0] * 256 + c) * 256 + kq];
      if (b0 + 1 < n) v1 = x[((size_t)idx[start + b0 + 1] * 256 + c) * 256 + kq];
      pk[m] = (unsigned)f2bf(v0) | ((unsigned)f2bf(v1) << 16);
    }
    XT4[kq * 5 + bh * 2 + 0] = make_uint4(pk[0], pk[1], pk[2], pk[3]);
    XT4[kq * 5 + bh * 2 + 1] = make_uint4(pk[4], pk[5], pk[6], pk[7]);
    __syncthreads();
    bf16x8 af[8], bfr[4];
    #pragma unroll
    for (int i = 0; i < 8; ++i){
      int T = wr * 8 + i;
      af[i] = *reinterpret_cast<const bf16x8*>(&XT4[(T * 16 + lrow) * 5 + lhalf]);
    }
    #pragma unroll
    for (int jn = 0; jn < 4; ++jn){
      int T = wc * 4 + jn;
      bfr[jn] = *reinterpret_cast<const bf16x8*>(&XT4[(T * 16 + lrow) * 5 + lhalf]);
    }
    #pragma unroll
    for (int i = 0; i < 8; ++i)
      #pragma unroll
      for (int jn = 0; jn < 4; ++jn)
        acc[i][jn] = __builtin_amdgcn_mfma_f32_16x16x32_bf16(af[i], bfr[jn], acc[i][jn], 0, 0, 0);
  }
  __syncthreads();

  float invn = 1.0f / fmaxf((float)n, 1.0f);
  float* sigm = sig + (size_t)bid * MSZ;
  #pragma unroll
  for (int i = 0; i < 8; ++i){
    int Rb = (wr * 8 + i) * 16 + lhalf * 4;
    #pragma unroll
    for (int jn = 0; jn < 4; ++jn){
      int Cc = (wc * 4 + jn) * 16 + lrow;
      #pragma unroll
      for (int r = 0; r < 4; ++r){
        int R = Rb + r;
        float v = acc[i][jn][r] * invn + cov[R * 256 + Cc] - mlds[R] * mlds[Cc];
        sigm[R * 256 + Cc] = (Cc <= R) ? v : 0.0f;   // zero strict upper
      }
    }
  }
}

// ---------------- K3a helper: in-LDS 128x128 right-looking Cholesky (r13-verified) ----------------
__device__ void factor128_v13(float* __restrict__ LB, int t, float& ldacc){
  for (int kb = 0; kb < 4; ++kb){
    int j0 = kb * 32;
    // ---- (a) wave0: 4x4-blocked chol of 32x32 diag block
    if (t < 64){
      #pragma unroll 1
      for (int s8 = 0; s8 < 8; ++s8){
        int js = j0 + 4*s8;
        float a00 = LB[(js+0)*132 + js+0];
        float a10 = LB[(js+1)*132 + js+0], a11 = LB[(js+1)*132 + js+1];
        float a20 = LB[(js+2)*132 + js+0], a21 = LB[(js+2)*132 + js+1], a22 = LB[(js+2)*132 + js+2];
        float a30 = LB[(js+3)*132 + js+0], a31 = LB[(js+3)*132 + js+1], a32 = LB[(js+3)*132 + js+2], a33 = LB[(js+3)*132 + js+3];
        float l00 = sqrtf(a00);
        float i00 = 1.0f / l00;
        float l10 = a10 * i00, l20 = a20 * i00, l30 = a30 * i00;
        float l11 = sqrtf(a11 - l10*l10);
        float i11 = 1.0f / l11;
        float l21 = (a21 - l20*l10) * i11, l31 = (a31 - l30*l10) * i11;
        float l22 = sqrtf(a22 - l20*l20 - l21*l21);
        float i22 = 1.0f / l22;
        float l32 = (a32 - l30*l20 - l31*l21) * i22;
        float l33 = sqrtf(a33 - l30*l30 - l31*l31 - l32*l32);
        float i33 = 1.0f / l33;
        if (t == 0){
          LB[(js+0)*132 + js+0] = l00;
          LB[(js+1)*132 + js+0] = l10; LB[(js+1)*132 + js+1] = l11;
          LB[(js+2)*132 + js+0] = l20; LB[(js+2)*132 + js+1] = l21; LB[(js+2)*132 + js+2] = l22;
          LB[(js+3)*132 + js+0] = l30; LB[(js+3)*132 + js+1] = l31; LB[(js+3)*132 + js+2] = l32; LB[(js+3)*132 + js+3] = l33;
          ldacc += logf(l00) + logf(l11) + logf(l22) + logf(l33);
        }
        int cnt2 = 28 - 4*s8;
        int r = js + 4 + t;
        if (t < cnt2){
          float w0 = LB[r*132 + js+0], w1 = LB[r*132 + js+1], w2 = LB[r*132 + js+2], w3 = LB[r*132 + js+3];
          w0 = w0 * i00;
          w1 = (w1 - l10*w0) * i11;
          w2 = (w2 - l20*w0 - l21*w1) * i22;
          w3 = (w3 - l30*w0 - l31*w1 - l32*w2) * i33;
          LB[r*132 + js+0] = w0; LB[r*132 + js+1] = w1; LB[r*132 + js+2] = w2; LB[r*132 + js+3] = w3;
          #pragma unroll 4
          for (int cq2 = js + 4; cq2 <= r; ++cq2){
            f32x4 Lc = *(const f32x4*)&LB[cq2*132 + js];
            LB[r*132 + cq2] -= w0*Lc.x + w1*Lc.y + w2*Lc.z + w3*Lc.w;
          }
        }
      }
    }
    __syncthreads();
    int nr = 96 - j0;              // panel rows below diag
    if (nr > 0){
      // ---- (b) panel: per-row forward substitution (register w, broadcast LDS reads)
      if (t < nr){
        int row = j0 + 32 + t;
        float w[32];
        #pragma unroll
        for (int q = 0; q < 8; ++q){
          f32x4 v = *(const f32x4*)&LB[row*132 + j0 + 4*q];
          w[4*q] = v.x; w[4*q+1] = v.y; w[4*q+2] = v.z; w[4*q+3] = v.w;
        }
        #pragma unroll
        for (int cc = 0; cc < 32; ++cc){
          float s = w[cc];
          #pragma unroll
          for (int p = 0; p < cc; ++p) s -= LB[(j0+cc)*132 + j0 + p] * w[p];
          w[cc] = s / LB[(j0+cc)*132 + j0 + cc];
        }
        #pragma unroll
        for (int q = 0; q < 8; ++q){
          f32x4 v; v.x = w[4*q]; v.y = w[4*q+1]; v.z = w[4*q+2]; v.w = w[4*q+3];
          *(f32x4*)&LB[row*132 + j0 + 4*q] = v;
        }
      }
      __syncthreads();
      // ---- (c) trailing rank-32 update: 4x4 tiles over lower tile-triangle
      int nt = nr >> 2;
      int Tt = nt*(nt+1)/2;        // 300 / 136 / 36
      if (t < Tt){
        int R, C; tri_decode(t, R, C);
        int rb = j0+32+4*R, cb = j0+32+4*C;
        float s[16];
        #pragma unroll
        for (int q = 0; q < 16; ++q) s[q] = 0.f;
        #pragma unroll 4
        for (int qc = 0; qc < 8; ++qc){
          f32x4 a0 = *(const f32x4*)&LB[(rb+0)*132 + j0 + 4*qc];
          f32x4 a1 = *(const f32x4*)&LB[(rb+1)*132 + j0 + 4*qc];
          f32x4 a2 = *(const f32x4*)&LB[(rb+2)*132 + j0 + 4*qc];
          f32x4 a3 = *(const f32x4*)&LB[(rb+3)*132 + j0 + 4*qc];
          f32x4 b0 = *(const f32x4*)&LB[(cb+0)*132 + j0 + 4*qc];
          f32x4 b1 = *(const f32x4*)&LB[(cb+1)*132 + j0 + 4*qc];
          f32x4 b2 = *(const f32x4*)&LB[(cb+2)*132 + j0 + 4*qc];
          f32x4 b3 = *(const f32x4*)&LB[(cb+3)*132 + j0 + 4*qc];
          s[0]+=dot4(a0,b0);  s[1]+=dot4(a0,b1);  s[2]+=dot4(a0,b2);  s[3]+=dot4(a0,b3);
          s[4]+=dot4(a1,b0);  s[5]+=dot4(a1,b1);  s[6]+=dot4(a1,b2);  s[7]+=dot4(a1,b3);
          s[8]+=dot4(a2,b0);  s[9]+=dot4(a2,b1);  s[10]+=dot4(a2,b2); s[11]+=dot4(a2,b3);
          s[12]+=dot4(a3,b0); s[13]+=dot4(a3,b1); s[14]+=dot4(a3,b2); s[15]+=dot4(a3,b3);
        }
        #pragma unroll
        for (int i2 = 0; i2 < 4; ++i2)
          #pragma unroll
          for (int jl = 0; jl < 4; ++jl)
            LB[(rb+i2)*132 + cb+jl] -= s[i2*4+jl];
      }
    }
    __syncthreads();
  }
}

// ---------------- K3a: two-level Schur Cholesky, 71.8 KB dynamic LDS (r13-verified) ----------------
__global__ __launch_bounds__(512) void k3a_chol(float* __restrict__ sig, float* __restrict__ logdet, int c0){
  extern __shared__ float smem[];
  float* LB = smem;                 // 128*132 = 16896 floats
  float* LT = smem + 16896;         // 1056 floats (staged 32x32 L blocks, stride 33)
  int t = threadIdx.x;
  int bid = blockIdx.x;
  int l = bid & 1, c = c0 + (bid >> 1);
  float* A = sig + (size_t)bid * MSZ;
  float ldacc = 0.f;

  // ==== P1: load A11, factor in LDS, write L11 ====
  for (int i = t; i < 4096; i += 512){
    int r = i >> 5, q = i & 31;
    *(f32x4*)&LB[r*132 + 4*q] = *(const f32x4*)&A[(size_t)r*256 + 4*q];
  }
  __syncthreads();
  factor128_v13(LB, t, ldacc);
  for (int i = t; i < 4096; i += 512){
    int r = i >> 5, q = i & 31;
    f32x4 v = *(const f32x4*)&LB[r*132 + 4*q];
    int cb = 4*q;
    v.x = (cb+0 <= r) ? v.x : 0.f;
    v.y = (cb+1 <= r) ? v.y : 0.f;
    v.z = (cb+2 <= r) ? v.z : 0.f;
    v.w = (cb+3 <= r) ? v.w : 0.f;
    *(f32x4*)&A[(size_t)r*256 + 4*q] = v;
  }
  __syncthreads();

  // ==== P2: TRSM L21 = A21 * L11^-T; W in LB; L11 blocks staged from global ====
  {
    int r2 = t >> 2, g = t & 3;
    for (int kb = 0; kb < 4; ++kb){
      f32x4 v0 = *(const f32x4*)&A[(size_t)(128+r2)*256 + 32*kb + 8*g];
      f32x4 v1 = *(const f32x4*)&A[(size_t)(128+r2)*256 + 32*kb + 8*g + 4];
      float accv[8] = {v0.x, v0.y, v0.z, v0.w, v1.x, v1.y, v1.z, v1.w};
      for (int p = 0; p < kb; ++p){
        __syncthreads();   // prior LT readers done
        for (int i = t; i < 1024; i += 512){
          int j = i & 31, q = i >> 5;
          LT[q*33 + j] = A[(size_t)(32*kb + j)*256 + 32*p + q];   // LT[q][j] = L11[32kb+j][32p+q]
        }
        __syncthreads();
        f32x4 wv[8];
        #pragma unroll
        for (int q = 0; q < 8; ++q) wv[q] = *(const f32x4*)&LB[r2*132 + 32*p + 4*q];
        #pragma unroll
        for (int q4 = 0; q4 < 8; ++q4)
          #pragma unroll
          for (int jl = 0; jl < 8; ++jl)
            accv[jl] -= wv[q4].x * LT[(4*q4+0)*33 + 8*g+jl]
                      + wv[q4].y * LT[(4*q4+1)*33 + 8*g+jl]
                      + wv[q4].z * LT[(4*q4+2)*33 + 8*g+jl]
                      + wv[q4].w * LT[(4*q4+3)*33 + 8*g+jl];
      }
      #pragma unroll
      for (int jl = 0; jl < 8; ++jl) LB[r2*132 + 32*kb + 8*g + jl] = accv[jl];
      __syncthreads();   // LB writes visible; prior LT readers done
      for (int i = t; i < 1024; i += 512){
        int cc = i >> 5, p = i & 31;
        LT[cc*33 + p] = A[(size_t)(32*kb + cc)*256 + 32*kb + p];  // L[cc][p]
      }
      __syncthreads();
      if (t < 128){      // per-row substitution vs diag block
        float w[32];
        #pragma unroll
        for (int q = 0; q < 8; ++q){
          f32x4 v = *(const f32x4*)&LB[t*132 + 32*kb + 4*q];
          w[4*q] = v.x; w[4*q+1] = v.y; w[4*q+2] = v.z; w[4*q+3] = v.w;
        }
        #pragma unroll
        for (int cc = 0; cc < 32; ++cc){
          float s = w[cc];
          #pragma unroll
          for (int p = 0; p < cc; ++p) s -= LT[cc*33 + p] * w[p];
          w[cc] = s / LT[cc*33 + cc];
        }
        #pragma unroll
        for (int q = 0; q < 8; ++q){
          f32x4 v; v.x = w[4*q]; v.y = w[4*q+1]; v.z = w[4*q+2]; v.w = w[4*q+3];
          *(f32x4*)&LB[t*132 + 32*kb + 4*q] = v;
        }
      }
      __syncthreads();
    }
    for (int i = t; i < 4096; i += 512){
      int rr = i >> 5, q = i & 31;
      *(f32x4*)&A[(size_t)(128+rr)*256 + 4*q] = *(const f32x4*)&LB[rr*132 + 4*q];
    }
  }

  // ==== P3: SYRK A22' = A22 - L21*L21^T (stream A22, dots vs LDS L21, regs hold) ====
  float s1[16], s2[16];
  int R1 = 0, C1 = 0, R2 = 0, C2 = 0;
  bool v1 = (t < 528), v2 = (t < 16);
  if (v1) tri_decode(t, R1, C1);
  if (v2) tri_decode(512 + t, R2, C2);
  #pragma unroll
  for (int q = 0; q < 16; ++q){ s1[q] = 0.f; s2[q] = 0.f; }
  if (v1){
    for (int qc = 0; qc < 32; ++qc){
      f32x4 a0 = *(const f32x4*)&LB[(4*R1+0)*132 + 4*qc];
      f32x4 a1 = *(const f32x4*)&LB[(4*R1+1)*132 + 4*qc];
      f32x4 a2 = *(const f32x4*)&LB[(4*R1+2)*132 + 4*qc];
      f32x4 a3 = *(const f32x4*)&LB[(4*R1+3)*132 + 4*qc];
      f32x4 b0 = *(const f32x4*)&LB[(4*C1+0)*132 + 4*qc];
      f32x4 b1 = *(const f32x4*)&LB[(4*C1+1)*132 + 4*qc];
      f32x4 b2 = *(const f32x4*)&LB[(4*C1+2)*132 + 4*qc];
      f32x4 b3 = *(const f32x4*)&LB[(4*C1+3)*132 + 4*qc];
      s1[0]+=dot4(a0,b0);  s1[1]+=dot4(a0,b1);  s1[2]+=dot4(a0,b2);  s1[3]+=dot4(a0,b3);
      s1[4]+=dot4(a1,b0);  s1[5]+=dot4(a1,b1);  s1[6]+=dot4(a1,b2);  s1[7]+=dot4(a1,b3);
      s1[8]+=dot4(a2,b0);  s1[9]+=dot4(a2,b1);  s1[10]+=dot4(a2,b2); s1[11]+=dot4(a2,b3);
      s1[12]+=dot4(a3,b0); s1[13]+=dot4(a3,b1); s1[14]+=dot4(a3,b2); s1[15]+=dot4(a3,b3);
    }
    #pragma unroll
    for (int i2 = 0; i2 < 4; ++i2){
      f32x4 av = *(const f32x4*)&A[(size_t)(128+4*R1+i2)*256 + 128 + 4*C1];
      s1[i2*4+0] = av.x - s1[i2*4+0];
      s1[i2*4+1] = av.y - s1[i2*4+1];
      s1[i2*4+2] = av.z - s1[i2*4+2];
      s1[i2*4+3] = av.w - s1[i2*4+3];
    }
  }
  if (v2){
    for (int qc = 0; qc < 32; ++qc){
      f32x4 a0 = *(const f32x4*)&LB[(4*R2+0)*132 + 4*qc];
      f32x4 a1 = *(const f32x4*)&LB[(4*R2+1)*132 + 4*qc];
      f32x4 a2 = *(const f32x4*)&LB[(4*R2+2)*132 + 4*qc];
      f32x4 a3 = *(const f32x4*)&LB[(4*R2+3)*132 + 4*qc];
      f32x4 b0 = *(const f32x4*)&LB[(4*C2+0)*132 + 4*qc];
      f32x4 b1 = *(const f32x4*)&LB[(4*C2+1)*132 + 4*qc];
      f32x4 b2 = *(const f32x4*)&LB[(4*C2+2)*132 + 4*qc];
      f32x4 b3 = *(const f32x4*)&LB[(4*C2+3)*132 + 4*qc];
      s2[0]+=dot4(a0,b0);  s2[1]+=dot4(a0,b1);  s2[2]+=dot4(a0,b2);  s2[3]+=dot4(a0,b3);
      s2[4]+=dot4(a1,b0);  s2[5]+=dot4(a1,b1);  s2[6]+=dot4(a1,b2);  s2[7]+=dot4(a1,b3);
      s2[8]+=dot4(a2,b0);  s2[9]+=dot4(a2,b1);  s2[10]+=dot4(a2,b2); s2[11]+=dot4(a2,b3);
      s2[12]+=dot4(a3,b0); s2[13]+=dot4(a3,b1); s2[14]+=dot4(a3,b2); s2[15]+=dot4(a3,b3);
    }
    #pragma unroll
    for (int i2 = 0; i2 < 4; ++i2){
      f32x4 av = *(const f32x4*)&A[(size_t)(128+4*R2+i2)*256 + 128 + 4*C2];
      s2[i2*4+0] = av.x - s2[i2*4+0];
      s2[i2*4+1] = av.y - s2[i2*4+1];
      s2[i2*4+2] = av.z - s2[i2*4+2];
      s2[i2*4+3] = av.w - s2[i2*4+3];
    }
  }
  __syncthreads();     // all reads of LB (L21) complete
  if (v1){
    #pragma unroll
    for (int i2 = 0; i2 < 4; ++i2)
      #pragma unroll
      for (int jl = 0; jl < 4; ++jl)
        LB[(4*R1+i2)*132 + 4*C1+jl] = s1[i2*4+jl];
  }
  if (v2){
    #pragma unroll
    for (int i2 = 0; i2 < 4; ++i2)
      #pragma unroll
      for (int jl = 0; jl < 4; ++jl)
        LB[(4*R2+i2)*132 + 4*C2+jl] = s2[i2*4+jl];
  }
  __syncthreads();

  // ==== P4: factor A22' in LDS; write L22 ====
  factor128_v13(LB, t, ldacc);
  for (int i = t; i < 4096; i += 512){
    int r = i >> 5, q = i & 31;
    f32x4 v = *(const f32x4*)&LB[r*132 + 4*q];
    int cb = 4*q;
    v.x = (cb+0 <= r) ? v.x : 0.f;
    v.y = (cb+1 <= r) ? v.y : 0.f;
    v.z = (cb+2 <= r) ? v.z : 0.f;
    v.w = (cb+3 <= r) ? v.w : 0.f;
    *(f32x4*)&A[(size_t)(128+r)*256 + 128 + 4*q] = v;
  }
  if (t < 32){
    float v = ldacc;
    #pragma unroll
    for (int m = 1; m < 32; m <<= 1) v += __shfl_xor(v, m);
    if (t == 0) logdet[l * 256 + c] = 2.0f * v;
  }
}

// ---------------- K3b: TRSM L1 W = L0 (column-per-thread) + fused y-solve (wave0) ----------------
// trp = ||W||_F^2; y = L1^-1 d solved per-RB on wave 0 using the already-staged L1blk;
// klp[c] written directly (k3c eliminated).
__global__ __launch_bounds__(256) void k3b_trsm(const float* __restrict__ means, float* __restrict__ sig,
    const float* __restrict__ logdet, float* __restrict__ klp, int c0){
  __shared__ float L1blk[32 * 256];   // 32 KB
  __shared__ float yl[256];
  __shared__ float dl[256];
  __shared__ float redw[4], redq[4];
  int t = threadIdx.x, b = blockIdx.x;
  int c = c0 + b;
  int lane = t & 63, wav = t >> 6;
  const float* L1 = sig + (size_t)(b * 2 + 1) * MSZ;
  float* W = sig + (size_t)(b * 2) * MSZ;     // starts as L0, becomes W
  float tracc = 0.f;

  // stage d = m1 - m0; pre-zero y (removes need for p<r predication: upper-L is 0)
  if (t < 256){
    dl[t] = means[(size_t)(256 + c) * 256 + t] - means[(size_t)c * 256 + t];
    yl[t] = 0.f;
  }

  for (int RB = 0; RB < 8; ++RB){
    int r0 = RB * 32;
    __syncthreads();
    for (int i = t; i < 32 * 256; i += 256)
      L1blk[i] = L1[(size_t)(r0 + (i >> 8)) * 256 + (i & 255)];
    __syncthreads();

    // ---- wave 0: y-solve rows r0..r0+31 (L1 strict-upper is zero; yl pre-zeroed,
    // so the 4-term dot needs no predication). Lockstep write->read within the wave.
    if (wav == 0){
      for (int rr = 0; rr < 32; ++rr){
        int r = r0 + rr;
        const float* row = &L1blk[rr * 256];
        float part = row[lane] * yl[lane] + row[lane + 64] * yl[lane + 64]
                   + row[lane + 128] * yl[lane + 128] + row[lane + 192] * yl[lane + 192];
        #pragma unroll
        for (int m = 1; m < 64; m <<= 1) part += __shfl_xor(part, m);
        float val = (dl[r] - part) / row[r];
        if (lane == 0) yl[r] = val;
      }
    }

    float acc[32];
    #pragma unroll
    for (int r = 0; r < 32; ++r) acc[r] = W[(size_t)(r0 + r) * 256 + t];

    for (int p = 0; p < r0; p += 8){
      float wv[8];
      #pragma unroll
      for (int q = 0; q < 8; ++q) wv[q] = W[(size_t)(p + q) * 256 + t];
      #pragma unroll
      for (int r = 0; r < 32; ++r){
        const f32x4 La = *(const f32x4*)&L1blk[r * 256 + p];
        const f32x4 Lb = *(const f32x4*)&L1blk[r * 256 + p + 4];
        acc[r] -= La.x * wv[0] + La.y * wv[1] + La.z * wv[2] + La.w * wv[3]
                + Lb.x * wv[4] + Lb.y * wv[5] + Lb.z * wv[6] + Lb.w * wv[7];
      }
    }
    // in-block forward substitution (column-private, no barriers)
    #pragma unroll
    for (int rr = 0; rr < 32; ++rr){
      float v = acc[rr];
      #pragma unroll
      for (int q = 0; q < rr; ++q)
        v -= L1blk[rr * 256 + r0 + q] * acc[q];
      v /= L1blk[rr * 256 + r0 + rr];
      acc[rr] = v;
      tracc += v * v;
      W[(size_t)(r0 + rr) * 256 + t] = v;
    }
  }
  __syncthreads();   // yl complete + all tracc done
  // quad = ||y||^2
  float qv = (t < 256) ? yl[t] * yl[t] : 0.f;
  #pragma unroll
  for (int m = 1; m < 64; m <<= 1) qv += __shfl_xor(qv, m);
  #pragma unroll
  for (int m = 1; m < 64; m <<= 1) tracc += __shfl_xor(tracc, m);
  if (lane == 0){ redw[wav] = tracc; redq[wav] = qv; }
  __syncthreads();
  if (t == 0){
    float tr = redw[0] + redw[1] + redw[2] + redw[3];
    float qq = redq[0] + redq[1] + redq[2] + redq[3];
    klp[c] = 0.5f * (tr + qq - 256.0f + logdet[256 + c] - logdet[c]);
  }
}

// ---------------- K4: final reduce + scale ----------------
__global__ void k4_final(const float* __restrict__ klp, const int* __restrict__ cnt, float* __restrict__ out){
  __shared__ float red[256];
  int t = threadIdx.x;
  red[t] = klp[t];
  __syncthreads();
  for (int s = 128; s > 0; s >>= 1){
    if (t < s) red[t] += red[t + s];
    __syncthreads();
  }
  if (t == 0){
    float n0 = (float)cnt[0], n1 = (float)cnt[1];
    out[0] = red[0] * n0 * n1 / 256.0f / 512.0f / 512.0f;
  }
}

extern "C" void kernel_launch(void* const* d_in, const int* in_sizes, int n_in,
                              void* d_out, int out_size, void* d_ws, size_t ws_size,
                              hipStream_t stream){
  (void)in_sizes; (void)n_in; (void)out_size;
  const float* mu  = (const float*)d_in[0];
  const float* cov = (const float*)d_in[1];
  const int*   lab = (const int*)d_in[2];
  float* out = (float*)d_out;
  char* ws = (char*)d_ws;
  // ws layout (bytes):
  // means  @ 0        (524288)   trp @ 524288 (1024, unused)   klp @ 525312 (1024)
  // logdet @ 526336   (2048)     cnt @ 528384 (8)      idx @ 528392 (2048)
  // sig    @ 1048576  (ch*2 full 256x256 fp32 squares)
  float* means  = (float*)ws;
  float* klp    = (float*)(ws + 525312);
  float* logdet = (float*)(ws + 526336);
  int*   cnt    = (int*)  (ws + 528384);
  int*   idx    = (int*)  (ws + 528392);
  float* sig    = (float*)(ws + 1048576);
  const size_t base = 1048576;

  int ch = 0;
  if      (ws_size >= base + (size_t)256 * 2 * MSZ * 4) ch = 256;
  else if (ws_size >= base + (size_t)64  * 2 * MSZ * 4) ch = 64;
  else if (ws_size >= base + (size_t)16  * 2 * MSZ * 4) ch = 16;
  else if (ws_size >= base + (size_t)4   * 2 * MSZ * 4) ch = 4;
  else if (ws_size >= base + (size_t)1   * 2 * MSZ * 4) ch = 1;
  if (ch == 0){
    k_sentinel<<<1, 1, 0, stream>>>(out);
    return;
  }

  const int k3a_lds = 17952 * 4;   // 71808 B dynamic LDS
  (void)hipFuncSetAttribute((const void*)k3a_chol,
                            hipFuncAttributeMaxDynamicSharedMemorySize, k3a_lds);

  k0_partition<<<1, 512, 0, stream>>>(lab, cnt, idx);
  k1_means<<<256, 1024, 0, stream>>>(mu, lab, cnt, means);
  for (int c0 = 0; c0 < 256; c0 += ch){
    k2_gram<<<ch * 2, 512, 0, stream>>>(mu, cov, means, cnt, idx, sig, c0);
    k3a_chol<<<ch * 2, 512, k3a_lds, stream>>>(sig, logdet, c0);
    k3b_trsm<<<ch, 256, 0, stream>>>(means, sig, logdet, klp, c0);
  }
  k4_final<<<1, 256, 0, stream>>>(klp, cnt, out);
}